// Round 15
// baseline (1699.517 us; speedup 1.0000x reference)
//
#include <hip/hip_runtime.h>
#include <hip/hip_fp16.h>

#define NNODES 200000
#define NEDGES 6400000
#define NENT   2048
#define CH     8
#define HID    32
#define NCONV  8
#define BN_EPS 1e-5f

#define BSZ    512                                  // nodes per dst-bucket
#define NBUCK  ((NNODES + BSZ - 1) / BSZ)           // 391
#define HB     (NBUCK/2)                            // src-bin half boundary (195)
#define CHUNK  4096
#define NCHUNK ((NEDGES + CHUNK - 1) / CHUNK)       // 1563
#define SPAD   16                                   // stats padding: one 64B line per channel-stat
#define SUBCAP 12288                                // staged edges per half-block (48 KB)

#define FXSCALE   2097152.0f                        // 2^21 fixed-point scale for LDS int accumulation
#define FXINV     (1.0f/2097152.0f)

// ---------------- phase A: per-chunk bucket histogram ----------------
__global__ __launch_bounds__(256) void k_chist(const int* __restrict__ dst, int* __restrict__ cnt, int E){
  __shared__ int hist[NBUCK];
  for(int t=threadIdx.x; t<NBUCK; t+=256) hist[t]=0;
  __syncthreads();
  int e0 = blockIdx.x*CHUNK;
  int n = min(CHUNK, E-e0);
  for(int i=threadIdx.x; i<n; i+=256) atomicAdd(&hist[dst[e0+i]>>9], 1);
  __syncthreads();
  for(int t=threadIdx.x; t<NBUCK; t+=256) cnt[(size_t)blockIdx.x*NBUCK + t] = hist[t];
}

// ---------------- phase B1: per-bucket exclusive scan over chunks ----------------
__global__ __launch_bounds__(256) void k_cscan(int* __restrict__ cnt, int* __restrict__ total){
  int b = blockIdx.x;
  __shared__ int sd[256];
  int carry = 0;
  for(int base=0; base<NCHUNK; base+=256){
    int c = base + threadIdx.x;
    int v = (c<NCHUNK) ? cnt[(size_t)c*NBUCK + b] : 0;
    sd[threadIdx.x] = v; __syncthreads();
    #pragma unroll
    for(int o=1; o<256; o<<=1){
      int x = (threadIdx.x>=o) ? sd[threadIdx.x-o] : 0;
      __syncthreads();
      sd[threadIdx.x] += x;
      __syncthreads();
    }
    if(c<NCHUNK) cnt[(size_t)c*NBUCK + b] = carry + sd[threadIdx.x] - v;  // exclusive
    carry += sd[255];
    __syncthreads();
  }
  if(threadIdx.x==0) total[b] = carry;
}

// ---------------- phase B2: bucket base scan ----------------
__global__ __launch_bounds__(512) void k_bscan(const int* __restrict__ total, int* __restrict__ bbase){
  __shared__ int sd[512];
  int t = threadIdx.x;
  int v = (t<NBUCK) ? total[t] : 0;
  sd[t] = v; __syncthreads();
  #pragma unroll
  for(int o=1; o<512; o<<=1){
    int x = (t>=o) ? sd[t-o] : 0;
    __syncthreads();
    sd[t] += x;
    __syncthreads();
  }
  if(t<NBUCK) bbase[t] = sd[t] - v;
  if(t==511) bbase[NBUCK] = sd[511];   // == NEDGES
}

// ---------------- phase C: LDS counting-sort scatter into bucket runs ----------------
// packed edge = (dst_local<<18) | src   (src<2^18, dst_local<512)
__global__ __launch_bounds__(512) void k_bin(const int* __restrict__ src, const int* __restrict__ dst,
                                             const int* __restrict__ cnt, const int* __restrict__ bbase,
                                             unsigned int* __restrict__ binned, int E){
  __shared__ int hist[NBUCK], excl[NBUCK], cur[NBUCK], base[NBUCK];
  __shared__ unsigned int pin[CHUNK];
  __shared__ unsigned short bk_in[CHUNK];
  __shared__ unsigned int sorted[CHUNK];
  __shared__ unsigned short sbkt[CHUNK];
  __shared__ int sd[512];
  int c = blockIdx.x;
  int e0 = c*CHUNK, n = min(CHUNK, E-e0);
  for(int t=threadIdx.x; t<NBUCK; t+=512) hist[t]=0;
  __syncthreads();
  for(int i=threadIdx.x; i<n; i+=512){
    int s = src[e0+i], d = dst[e0+i];
    int b = d>>9;
    pin[i]   = ((unsigned)(d & (BSZ-1))<<18) | (unsigned)s;
    bk_in[i] = (unsigned short)b;
    atomicAdd(&hist[b], 1);
  }
  __syncthreads();
  int t = threadIdx.x;
  int hv = (t<NBUCK) ? hist[t] : 0;
  sd[t] = hv; __syncthreads();
  #pragma unroll
  for(int o=1; o<512; o<<=1){
    int x = (t>=o) ? sd[t-o] : 0;
    __syncthreads();
    sd[t] += x;
    __syncthreads();
  }
  if(t<NBUCK){
    int ex = sd[t] - hv;
    excl[t] = ex; cur[t] = ex;
    base[t] = bbase[t] + cnt[(size_t)c*NBUCK + t];
  }
  __syncthreads();
  for(int i=threadIdx.x; i<n; i+=512){
    int b = bk_in[i];
    int slot = atomicAdd(&cur[b], 1);
    sorted[slot] = pin[i];
    sbkt[slot]   = (unsigned short)b;
  }
  __syncthreads();
  for(int i=threadIdx.x; i<n; i+=512){
    int b = sbkt[i];
    binned[ base[b] + (i - excl[b]) ] = sorted[i];   // contiguous runs per bucket
  }
}

// ---------------- phase D: per-bucket SRC-BIN sort, LDS-staged coalesced output ----------------
// 2 blocks per bucket (src-bin halves). Scatter into LDS stage, stream out coalesced.
__global__ __launch_bounds__(512) void k_sub(const unsigned int* __restrict__ binned,
                                             const int* __restrict__ bbase,
                                             unsigned int* __restrict__ binned2,
                                             float* __restrict__ dinv, int N){
  __shared__ int hd[BSZ];        // dst_local degree histogram (half 0 only)
  __shared__ int hs[NBUCK];      // src-bin histogram
  __shared__ int cur[NBUCK];
  __shared__ int sd[512];
  __shared__ int hbase_s;
  __shared__ unsigned int stage[SUBCAP];   // 48 KB
  int b = blockIdx.x >> 1, half = blockIdx.x & 1;
  int t = threadIdx.x;
  hd[t] = 0;
  if(t < NBUCK) hs[t] = 0;
  __syncthreads();
  int s0 = bbase[b], s1 = bbase[b+1];
  if(half == 0){
    for(int i=s0+t; i<s1; i+=512){
      unsigned p = binned[i];
      atomicAdd(&hd[p>>18], 1);
      atomicAdd(&hs[(p & 0x3FFFF)>>9], 1);
    }
  } else {
    for(int i=s0+t; i<s1; i+=512){
      unsigned p = binned[i];
      atomicAdd(&hs[(p & 0x3FFFF)>>9], 1);
    }
  }
  __syncthreads();
  if(half == 0){
    int node = b*BSZ + t;
    if(node < N) dinv[node] = 1.0f / sqrtf((float)hd[t] + 1.0f);
  }
  // exclusive scan of src-bin histogram
  int hv = (t<NBUCK) ? hs[t] : 0;
  sd[t] = hv; __syncthreads();
  #pragma unroll
  for(int o=1; o<512; o<<=1){
    int x = (t>=o) ? sd[t-o] : 0;
    __syncthreads();
    sd[t] += x;
    __syncthreads();
  }
  int ex = sd[t] - hv;                     // prefix of bins < t
  if(t == HB) hbase_s = ex;                // edges in bins < HB
  __syncthreads();
  int lo = half ? hbase_s : 0;
  int hi = half ? (s1 - s0) : hbase_s;
  if(t < NBUCK) cur[t] = ex - lo;          // stage-relative cursor (valid for this half's bins)
  __syncthreads();
  int len = hi - lo;
  if(len <= SUBCAP){
    for(int i=s0+t; i<s1; i+=512){
      unsigned p = binned[i];
      int bin = (p & 0x3FFFF)>>9;
      bool mine = half ? (bin >= HB) : (bin < HB);
      if(mine){
        int slot = atomicAdd(&cur[bin], 1);
        stage[slot] = p;
      }
    }
    __syncthreads();
    for(int i=t; i<len; i+=512) binned2[s0 + lo + i] = stage[i];   // coalesced
  } else {                                 // degenerate fallback: direct scatter
    for(int i=s0+t; i<s1; i+=512){
      unsigned p = binned[i];
      int bin = (p & 0x3FFFF)>>9;
      bool mine = half ? (bin >= HB) : (bin < HB);
      if(mine){
        int slot = atomicAdd(&cur[bin], 1);
        binned2[s0 + lo + slot] = p;
      }
    }
  }
}

// ---------------- h init: embedding gather + stats[0] (fp32 atomics, padded lines) ----------------
__global__ __launch_bounds__(256) void k_init_h(const int* __restrict__ x, const float* __restrict__ emb,
                                                float* __restrict__ h, float* __restrict__ stats0, int N){
  int i = blockIdx.x*256 + threadIdx.x;
  float v[CH];
  #pragma unroll
  for(int c=0;c<CH;c++) v[c]=0.f;
  if(i < N){
    int tt = x[i];
    const float4* ep = (const float4*)(emb + (size_t)tt*CH);
    float4 a = ep[0], b = ep[1];
    float4* hp = (float4*)(h + (size_t)i*CH);
    hp[0] = a; hp[1] = b;
    v[0]=a.x; v[1]=a.y; v[2]=a.z; v[3]=a.w; v[4]=b.x; v[5]=b.y; v[6]=b.z; v[7]=b.w;
  }
  float s[CH], q[CH];
  #pragma unroll
  for(int c=0;c<CH;c++){ s[c]=v[c]; q[c]=v[c]*v[c]; }
  #pragma unroll
  for(int off=32; off>0; off>>=1){
    #pragma unroll
    for(int c=0;c<CH;c++){ s[c]+=__shfl_down(s[c],off); q[c]+=__shfl_down(q[c],off); }
  }
  __shared__ float ls[4][2*CH];
  int wave = threadIdx.x>>6, lane = threadIdx.x&63;
  if(lane==0){
    #pragma unroll
    for(int c=0;c<CH;c++){ ls[wave][c]=s[c]; ls[wave][CH+c]=q[c]; }
  }
  __syncthreads();
  if(threadIdx.x < 2*CH){
    float tsum = ls[0][threadIdx.x]+ls[1][threadIdx.x]+ls[2][threadIdx.x]+ls[3][threadIdx.x];
    unsafeAtomicAdd(&stats0[threadIdx.x*SPAD], tsum);
  }
}

// ---------------- per-node transform: fold BN in-block, hts16 = fp16((h@A+c0)*dinv) ----------------
__global__ __launch_bounds__(256) void k_ht(const float* __restrict__ h, const float* __restrict__ stats_l,
                                            const float* __restrict__ gamma, const float* __restrict__ beta,
                                            const float* __restrict__ convw,
                                            const float* __restrict__ dinv,
                                            __half* __restrict__ hts16, int l, int N){
  __shared__ float A[CH*CH], c0[CH], sA[CH], sT[CH];
  int t = threadIdx.x;
  if(t < CH){
    const float invN = 1.0f / (float)NNODES;
    float mu  = stats_l[t*SPAD]      * invN;
    float ex2 = stats_l[(CH+t)*SPAD] * invN;
    float var = ex2 - mu*mu;
    float r   = 1.0f / sqrtf(var + BN_EPS);
    float sc  = r * gamma[l*CH+t];
    sA[t] = sc;
    sT[t] = beta[l*CH+t] - mu*sc;
  }
  __syncthreads();
  if(t < CH*CH){
    int ci = t>>3, co = t&7;
    A[t] = sA[ci] * convw[(l*CH+ci)*CH+co];
  }
  if(t < CH){
    float a = 0.f;
    #pragma unroll
    for(int ci=0;ci<CH;ci++) a += sT[ci]*convw[(l*CH+ci)*CH+t];
    c0[t] = a;
  }
  __syncthreads();
  int i = blockIdx.x*blockDim.x + threadIdx.x;
  if(i >= N) return;
  const float4* hp = (const float4*)(h + (size_t)i*CH);
  float4 a = hp[0], b = hp[1];
  float v[CH] = {a.x,a.y,a.z,a.w,b.x,b.y,b.z,b.w};
  float o[CH];
  #pragma unroll
  for(int co=0;co<CH;co++) o[co]=c0[co];
  #pragma unroll
  for(int ci=0;ci<CH;ci++){
    float vv = v[ci];
    #pragma unroll
    for(int co=0;co<CH;co++) o[co] += vv*A[ci*CH+co];
  }
  float dn = dinv[i];
  union { __half hh[CH]; uint4 u; } pk;
  #pragma unroll
  for(int c=0;c<CH;c++) pk.hh[c] = __float2half(o[c]*dn);
  *(uint4*)(hts16 + (size_t)i*CH) = pk.u;
}

// ---------------- src-sorted bucket push, PARTIAL accumulate ----------------
// 2 blocks per bucket (disjoint edge-range halves), 512 threads, 8 lanes/edge.
// Fixed-point int LDS accumulation (native ds_add), partials to global pacc.
// 782 blocks -> 3.05/CU: balanced across ALL CUs (391x1024 packed only ~196 CUs).
__global__ __launch_bounds__(512) void k_push(const unsigned int* __restrict__ binned2,
                                              const int* __restrict__ bbase,
                                              const __half* __restrict__ hts16,
                                              int* __restrict__ pacc){
  __shared__ int acc[BSZ*CH];    // 16 KB, fixed-point 2^21
  int bh = blockIdx.x, b = bh>>1, half = bh&1;
  int t = threadIdx.x;
  #pragma unroll
  for(int i=t; i<BSZ*CH; i+=512) acc[i] = 0;
  __syncthreads();
  int s0 = bbase[b], s1 = bbase[b+1];
  int mid = s0 + ((s1 - s0) >> 1);
  int a0 = half ? mid : s0;
  int a1 = half ? s1  : mid;
  int lane8 = t & 7;
  int g = t >> 3;                          // 0..63
  for(int base = a0 + g*4; base < a1; base += 256){
    int m = a1 - base;
    if(m >= 4){
      unsigned p0 = binned2[base], p1 = binned2[base+1], p2 = binned2[base+2], p3 = binned2[base+3];
      float v0 = __half2float(hts16[(size_t)(p0 & 0x3FFFF)*CH + lane8]);
      float v1 = __half2float(hts16[(size_t)(p1 & 0x3FFFF)*CH + lane8]);
      float v2 = __half2float(hts16[(size_t)(p2 & 0x3FFFF)*CH + lane8]);
      float v3 = __half2float(hts16[(size_t)(p3 & 0x3FFFF)*CH + lane8]);
      atomicAdd(&acc[(p0>>18)*CH + lane8], __float2int_rn(v0*FXSCALE));
      atomicAdd(&acc[(p1>>18)*CH + lane8], __float2int_rn(v1*FXSCALE));
      atomicAdd(&acc[(p2>>18)*CH + lane8], __float2int_rn(v2*FXSCALE));
      atomicAdd(&acc[(p3>>18)*CH + lane8], __float2int_rn(v3*FXSCALE));
    } else {
      for(int i=0; i<m; i++){
        unsigned p = binned2[base+i];
        float v = __half2float(hts16[(size_t)(p & 0x3FFFF)*CH + lane8]);
        atomicAdd(&acc[(p>>18)*CH + lane8], __float2int_rn(v*FXSCALE));
      }
    }
  }
  __syncthreads();
  // dump partial: 4096 ints = 1024 int4, 512 threads x 2, coalesced
  int4* dst = (int4*)(pacc + (size_t)bh*BSZ*CH);
  const int4* src = (const int4*)acc;
  dst[t]       = src[t];
  dst[t + 512] = src[t + 512];
}

// ---------------- finalize: combine partials + self loop + residual + ReLU + stats ----------------
__global__ __launch_bounds__(256) void k_fin(const int* __restrict__ pacc,
                                             const __half* __restrict__ hts16,
                                             const float* __restrict__ dinv,
                                             const float* __restrict__ convb,
                                             float* __restrict__ h, float* __restrict__ stats_next,
                                             int l, int N){
  int tid = blockIdx.x*256 + threadIdx.x;      // node*8 + ch
  int lane8 = tid & 7;
  int node = tid >> 3;
  float val = 0.f;
  if(node < N){
    int b  = node >> 9;
    int dl = node & (BSZ-1);
    int a0 = pacc[((size_t)(2*b  )*BSZ + dl)*CH + lane8];
    int a1 = pacc[((size_t)(2*b+1)*BSZ + dl)*CH + lane8];
    float a = (float)(a0 + a1) * FXINV;
    float sv = __half2float(hts16[(size_t)node*CH + lane8]);   // self loop (pre-scaled)
    float hv = h[(size_t)node*CH + lane8];
    float r = hv + convb[l*CH + lane8] + dinv[node]*(a + sv);
    val = fmaxf(r, 0.f);
    h[(size_t)node*CH + lane8] = val;
  }
  float S = val, Q = val*val;
  S += __shfl_xor(S, 8);  Q += __shfl_xor(Q, 8);
  S += __shfl_xor(S, 16); Q += __shfl_xor(Q, 16);
  S += __shfl_xor(S, 32); Q += __shfl_xor(Q, 32);
  __shared__ float ls[4][2*CH];
  int wave = threadIdx.x>>6, wl = threadIdx.x&63;
  if(wl < CH){ ls[wave][wl] = S; ls[wave][CH+wl] = Q; }
  __syncthreads();
  if(threadIdx.x < 2*CH){
    float tsum = ls[0][threadIdx.x]+ls[1][threadIdx.x]+ls[2][threadIdx.x]+ls[3][threadIdx.x];
    unsafeAtomicAdd(&stats_next[threadIdx.x*SPAD], tsum);
  }
}

// ---------------- entries: u = xe@W1, v = xe@W2 + hb ----------------
__global__ __launch_bounds__(256) void k_uv(const int* __restrict__ entry, const float* __restrict__ h,
                                            const float* __restrict__ hw, const float* __restrict__ hb,
                                            float* __restrict__ u, float* __restrict__ v){
  __shared__ float w[2*CH*HID];
  __shared__ float b[HID];
  for(int t=threadIdx.x; t<2*CH*HID; t+=256) w[t]=hw[t];
  if(threadIdx.x<HID) b[threadIdx.x]=hb[threadIdx.x];
  __syncthreads();
  int k = blockIdx.x*blockDim.x + threadIdx.x;
  if(k >= NENT) return;
  int node = entry[k];
  const float4* hp = (const float4*)(h + (size_t)node*CH);
  float4 a = hp[0], b4 = hp[1];
  float xe[CH] = {a.x,a.y,a.z,a.w,b4.x,b4.y,b4.z,b4.w};
  #pragma unroll 4
  for(int c=0;c<HID;c++){
    float uu = 0.f, vv = b[c];
    #pragma unroll
    for(int ci=0;ci<CH;ci++){
      uu += xe[ci]*w[ci*HID+c];
      vv += xe[ci]*w[(CH+ci)*HID+c];
    }
    u[(size_t)k*HID+c] = uu;
    v[(size_t)k*HID+c] = vv;
  }
}

// ---------------- pairwise scorer ----------------
__global__ __launch_bounds__(256) void k_pair(const float* __restrict__ u, const float* __restrict__ v,
                                              const float* __restrict__ ow, const float* __restrict__ ob,
                                              float* __restrict__ out){
  __shared__ float us[16][HID+1];
  __shared__ float vs[64][HID+1];
  __shared__ float wo[HID];
  int tid = threadIdx.x;
  int jb = blockIdx.x*64, ib = blockIdx.y*16;
  for(int t=tid; t<16*HID; t+=256) us[t>>5][t&31] = u[(size_t)(ib + (t>>5))*HID + (t&31)];
  for(int t=tid; t<64*HID; t+=256) vs[t>>5][t&31] = v[(size_t)(jb + (t>>5))*HID + (t&31)];
  if(tid<HID) wo[tid]=ow[tid];
  __syncthreads();
  int tx = tid&63, ty = tid>>6;
  float a0=0.f, a1=0.f, a2=0.f, a3=0.f;
  #pragma unroll
  for(int c=0;c<HID;c++){
    float vv = vs[tx][c];
    float w  = wo[c];
    a0 += fmaxf(us[ty   ][c]+vv, 0.f)*w;
    a1 += fmaxf(us[ty+4 ][c]+vv, 0.f)*w;
    a2 += fmaxf(us[ty+8 ][c]+vv, 0.f)*w;
    a3 += fmaxf(us[ty+12][c]+vv, 0.f)*w;
  }
  float o0 = ob[0];
  size_t base = (size_t)ib*2048 + jb + tx;
  out[base + (size_t)(ty   )*2048] = a0+o0;
  out[base + (size_t)(ty+4 )*2048] = a1+o0;
  out[base + (size_t)(ty+8 )*2048] = a2+o0;
  out[base + (size_t)(ty+12)*2048] = a3+o0;
}

extern "C" void kernel_launch(void* const* d_in, const int* in_sizes, int n_in,
                              void* d_out, int out_size, void* d_ws, size_t ws_size,
                              hipStream_t stream){
  const int*   x     = (const int*)d_in[0];
  const int*   ei    = (const int*)d_in[1];
  const int*   entry = (const int*)d_in[2];
  const float* emb   = (const float*)d_in[3];
  const float* gamma = (const float*)d_in[4];
  const float* beta  = (const float*)d_in[5];
  const float* convw = (const float*)d_in[6];
  const float* convb = (const float*)d_in[7];
  const float* hw    = (const float*)d_in[8];
  const float* hb    = (const float*)d_in[9];
  const float* ow    = (const float*)d_in[10];
  const float* ob    = (const float*)d_in[11];
  const int* srcp = ei;
  const int* dstp = ei + NEDGES;

  // workspace (~67 MB; pacc aliases binned, which is dead after k_sub)
  char* ws = (char*)d_ws;
  size_t o = 0;
  auto alloc = [&](size_t bytes){ void* p = ws + o; o += (bytes + 255) & ~(size_t)255; return p; };
  int*      cnt    = (int*)     alloc((size_t)NCHUNK*NBUCK*4);   // 2.44 MB
  int*      total  = (int*)     alloc(NBUCK*4);
  int*      bbase  = (int*)     alloc((NBUCK+1)*4);
  unsigned* binned = (unsigned*)alloc((size_t)NEDGES*4);         // 25.6 MB (dst-bucket runs; dead after k_sub)
  unsigned* binned2= (unsigned*)alloc((size_t)NEDGES*4);         // 25.6 MB (src-sorted runs)
  float*    dinv   = (float*)   alloc(NNODES*4);
  float*    h      = (float*)   alloc((size_t)NNODES*CH*4);
  __half*   hts16  = (__half*)  alloc((size_t)NNODES*CH*2);      // 3.2 MB
  float*    stats  = (float*)   alloc((NCONV+1)*2*CH*SPAD*4);    // padded: one line per channel-stat
  float*    ub     = (float*)   alloc((size_t)NENT*HID*4);
  float*    vb     = (float*)   alloc((size_t)NENT*HID*4);
  int*      pacc   = (int*)binned;                               // 782*4096*4 = 12.8 MB, fits in binned
  (void)ws_size; (void)in_sizes; (void)n_in; (void)out_size;

  // ---- deterministic CSR build + src-bin re-sort ----
  k_chist<<<NCHUNK, 256, 0, stream>>>(dstp, cnt, NEDGES);
  k_cscan<<<NBUCK, 256, 0, stream>>>(cnt, total);
  k_bscan<<<1, 512, 0, stream>>>(total, bbase);
  k_bin  <<<NCHUNK, 512, 0, stream>>>(srcp, dstp, cnt, bbase, binned, NEDGES);
  k_sub  <<<NBUCK*2, 512, 0, stream>>>(binned, bbase, binned2, dinv, NNODES);

  hipMemsetAsync(stats, 0, (NCONV+1)*2*CH*SPAD*sizeof(float), stream);
  k_init_h<<<(NNODES+255)/256, 256, 0, stream>>>(x, emb, h, stats, NNODES);

  for(int l=0; l<NCONV; l++){
    k_ht  <<<(NNODES+255)/256, 256, 0, stream>>>(h, stats + (size_t)l*2*CH*SPAD, gamma, beta, convw,
                                                 dinv, hts16, l, NNODES);
    k_push<<<NBUCK*2, 512, 0, stream>>>(binned2, bbase, hts16, pacc);
    k_fin <<<(NNODES*CH+255)/256, 256, 0, stream>>>(pacc, hts16, dinv, convb, h,
                                                    stats + (size_t)(l+1)*2*CH*SPAD, l, NNODES);
  }

  k_uv<<<NENT/256, 256, 0, stream>>>(entry, h, hw, hb, ub, vb);
  dim3 pg(2048/64, 2048/16);
  k_pair<<<pg, 256, 0, stream>>>(ub, vb, ow, ob, (float*)d_out);
}

// Round 16
// 619.418 us; speedup vs baseline: 2.7437x; 2.7437x over previous
//
#include <hip/hip_runtime.h>
#include <hip/hip_fp16.h>

#define NNODES 200000
#define NEDGES 6400000
#define NENT   2048
#define CH     8
#define HID    32
#define NCONV  8
#define BN_EPS 1e-5f

#define BSZ    512                                  // nodes per dst-bucket
#define NBUCK  ((NNODES + BSZ - 1) / BSZ)           // 391
#define HB     (NBUCK/2)                            // src-bin half boundary (195)
#define CHUNK  4096
#define NCHUNK ((NEDGES + CHUNK - 1) / CHUNK)       // 1563
#define SPAD   16                                   // stats padding: one 64B line per channel-stat
#define SUBCAP 12288                                // staged edges per half-block (48 KB)
#define NFIN   512                                  // k_fin blocks (bounds same-line atomic count)

#define FXSCALE   2097152.0f                        // 2^21 fixed-point scale for LDS int accumulation
#define FXINV     (1.0f/2097152.0f)

// ---------------- phase A: per-chunk bucket histogram ----------------
__global__ __launch_bounds__(256) void k_chist(const int* __restrict__ dst, int* __restrict__ cnt, int E){
  __shared__ int hist[NBUCK];
  for(int t=threadIdx.x; t<NBUCK; t+=256) hist[t]=0;
  __syncthreads();
  int e0 = blockIdx.x*CHUNK;
  int n = min(CHUNK, E-e0);
  for(int i=threadIdx.x; i<n; i+=256) atomicAdd(&hist[dst[e0+i]>>9], 1);
  __syncthreads();
  for(int t=threadIdx.x; t<NBUCK; t+=256) cnt[(size_t)blockIdx.x*NBUCK + t] = hist[t];
}

// ---------------- phase B1: per-bucket exclusive scan over chunks ----------------
__global__ __launch_bounds__(256) void k_cscan(int* __restrict__ cnt, int* __restrict__ total){
  int b = blockIdx.x;
  __shared__ int sd[256];
  int carry = 0;
  for(int base=0; base<NCHUNK; base+=256){
    int c = base + threadIdx.x;
    int v = (c<NCHUNK) ? cnt[(size_t)c*NBUCK + b] : 0;
    sd[threadIdx.x] = v; __syncthreads();
    #pragma unroll
    for(int o=1; o<256; o<<=1){
      int x = (threadIdx.x>=o) ? sd[threadIdx.x-o] : 0;
      __syncthreads();
      sd[threadIdx.x] += x;
      __syncthreads();
    }
    if(c<NCHUNK) cnt[(size_t)c*NBUCK + b] = carry + sd[threadIdx.x] - v;  // exclusive
    carry += sd[255];
    __syncthreads();
  }
  if(threadIdx.x==0) total[b] = carry;
}

// ---------------- phase B2: bucket base scan ----------------
__global__ __launch_bounds__(512) void k_bscan(const int* __restrict__ total, int* __restrict__ bbase){
  __shared__ int sd[512];
  int t = threadIdx.x;
  int v = (t<NBUCK) ? total[t] : 0;
  sd[t] = v; __syncthreads();
  #pragma unroll
  for(int o=1; o<512; o<<=1){
    int x = (t>=o) ? sd[t-o] : 0;
    __syncthreads();
    sd[t] += x;
    __syncthreads();
  }
  if(t<NBUCK) bbase[t] = sd[t] - v;
  if(t==511) bbase[NBUCK] = sd[511];   // == NEDGES
}

// ---------------- phase C: LDS counting-sort scatter into bucket runs ----------------
// packed edge = (dst_local<<18) | src   (src<2^18, dst_local<512)
__global__ __launch_bounds__(512) void k_bin(const int* __restrict__ src, const int* __restrict__ dst,
                                             const int* __restrict__ cnt, const int* __restrict__ bbase,
                                             unsigned int* __restrict__ binned, int E){
  __shared__ int hist[NBUCK], excl[NBUCK], cur[NBUCK], base[NBUCK];
  __shared__ unsigned int pin[CHUNK];
  __shared__ unsigned short bk_in[CHUNK];
  __shared__ unsigned int sorted[CHUNK];
  __shared__ unsigned short sbkt[CHUNK];
  __shared__ int sd[512];
  int c = blockIdx.x;
  int e0 = c*CHUNK, n = min(CHUNK, E-e0);
  for(int t=threadIdx.x; t<NBUCK; t+=512) hist[t]=0;
  __syncthreads();
  for(int i=threadIdx.x; i<n; i+=512){
    int s = src[e0+i], d = dst[e0+i];
    int b = d>>9;
    pin[i]   = ((unsigned)(d & (BSZ-1))<<18) | (unsigned)s;
    bk_in[i] = (unsigned short)b;
    atomicAdd(&hist[b], 1);
  }
  __syncthreads();
  int t = threadIdx.x;
  int hv = (t<NBUCK) ? hist[t] : 0;
  sd[t] = hv; __syncthreads();
  #pragma unroll
  for(int o=1; o<512; o<<=1){
    int x = (t>=o) ? sd[t-o] : 0;
    __syncthreads();
    sd[t] += x;
    __syncthreads();
  }
  if(t<NBUCK){
    int ex = sd[t] - hv;
    excl[t] = ex; cur[t] = ex;
    base[t] = bbase[t] + cnt[(size_t)c*NBUCK + t];
  }
  __syncthreads();
  for(int i=threadIdx.x; i<n; i+=512){
    int b = bk_in[i];
    int slot = atomicAdd(&cur[b], 1);
    sorted[slot] = pin[i];
    sbkt[slot]   = (unsigned short)b;
  }
  __syncthreads();
  for(int i=threadIdx.x; i<n; i+=512){
    int b = sbkt[i];
    binned[ base[b] + (i - excl[b]) ] = sorted[i];   // contiguous runs per bucket
  }
}

// ---------------- phase D: per-bucket SRC-BIN sort, LDS-staged coalesced output ----------------
__global__ __launch_bounds__(512) void k_sub(const unsigned int* __restrict__ binned,
                                             const int* __restrict__ bbase,
                                             unsigned int* __restrict__ binned2,
                                             float* __restrict__ dinv, int N){
  __shared__ int hd[BSZ];        // dst_local degree histogram (half 0 only)
  __shared__ int hs[NBUCK];      // src-bin histogram
  __shared__ int cur[NBUCK];
  __shared__ int sd[512];
  __shared__ int hbase_s;
  __shared__ unsigned int stage[SUBCAP];   // 48 KB
  int b = blockIdx.x >> 1, half = blockIdx.x & 1;
  int t = threadIdx.x;
  hd[t] = 0;
  if(t < NBUCK) hs[t] = 0;
  __syncthreads();
  int s0 = bbase[b], s1 = bbase[b+1];
  if(half == 0){
    for(int i=s0+t; i<s1; i+=512){
      unsigned p = binned[i];
      atomicAdd(&hd[p>>18], 1);
      atomicAdd(&hs[(p & 0x3FFFF)>>9], 1);
    }
  } else {
    for(int i=s0+t; i<s1; i+=512){
      unsigned p = binned[i];
      atomicAdd(&hs[(p & 0x3FFFF)>>9], 1);
    }
  }
  __syncthreads();
  if(half == 0){
    int node = b*BSZ + t;
    if(node < N) dinv[node] = 1.0f / sqrtf((float)hd[t] + 1.0f);
  }
  // exclusive scan of src-bin histogram
  int hv = (t<NBUCK) ? hs[t] : 0;
  sd[t] = hv; __syncthreads();
  #pragma unroll
  for(int o=1; o<512; o<<=1){
    int x = (t>=o) ? sd[t-o] : 0;
    __syncthreads();
    sd[t] += x;
    __syncthreads();
  }
  int ex = sd[t] - hv;                     // prefix of bins < t
  if(t == HB) hbase_s = ex;                // edges in bins < HB
  __syncthreads();
  int lo = half ? hbase_s : 0;
  int hi = half ? (s1 - s0) : hbase_s;
  if(t < NBUCK) cur[t] = ex - lo;          // stage-relative cursor (valid for this half's bins)
  __syncthreads();
  int len = hi - lo;
  if(len <= SUBCAP){
    for(int i=s0+t; i<s1; i+=512){
      unsigned p = binned[i];
      int bin = (p & 0x3FFFF)>>9;
      bool mine = half ? (bin >= HB) : (bin < HB);
      if(mine){
        int slot = atomicAdd(&cur[bin], 1);
        stage[slot] = p;
      }
    }
    __syncthreads();
    for(int i=t; i<len; i+=512) binned2[s0 + lo + i] = stage[i];   // coalesced
  } else {                                 // degenerate fallback: direct scatter
    for(int i=s0+t; i<s1; i+=512){
      unsigned p = binned[i];
      int bin = (p & 0x3FFFF)>>9;
      bool mine = half ? (bin >= HB) : (bin < HB);
      if(mine){
        int slot = atomicAdd(&cur[bin], 1);
        binned2[s0 + lo + slot] = p;
      }
    }
  }
}

// ---------------- h init: embedding gather + stats[0] (fp32 atomics, padded lines) ----------------
__global__ __launch_bounds__(256) void k_init_h(const int* __restrict__ x, const float* __restrict__ emb,
                                                float* __restrict__ h, float* __restrict__ stats0, int N){
  int i = blockIdx.x*256 + threadIdx.x;
  float v[CH];
  #pragma unroll
  for(int c=0;c<CH;c++) v[c]=0.f;
  if(i < N){
    int tt = x[i];
    const float4* ep = (const float4*)(emb + (size_t)tt*CH);
    float4 a = ep[0], b = ep[1];
    float4* hp = (float4*)(h + (size_t)i*CH);
    hp[0] = a; hp[1] = b;
    v[0]=a.x; v[1]=a.y; v[2]=a.z; v[3]=a.w; v[4]=b.x; v[5]=b.y; v[6]=b.z; v[7]=b.w;
  }
  float s[CH], q[CH];
  #pragma unroll
  for(int c=0;c<CH;c++){ s[c]=v[c]; q[c]=v[c]*v[c]; }
  #pragma unroll
  for(int off=32; off>0; off>>=1){
    #pragma unroll
    for(int c=0;c<CH;c++){ s[c]+=__shfl_down(s[c],off); q[c]+=__shfl_down(q[c],off); }
  }
  __shared__ float ls[4][2*CH];
  int wave = threadIdx.x>>6, lane = threadIdx.x&63;
  if(lane==0){
    #pragma unroll
    for(int c=0;c<CH;c++){ ls[wave][c]=s[c]; ls[wave][CH+c]=q[c]; }
  }
  __syncthreads();
  if(threadIdx.x < 2*CH){
    float tsum = ls[0][threadIdx.x]+ls[1][threadIdx.x]+ls[2][threadIdx.x]+ls[3][threadIdx.x];
    unsafeAtomicAdd(&stats0[threadIdx.x*SPAD], tsum);
  }
}

// ---------------- per-node transform: fold BN in-block, hts16 = fp16((h@A+c0)*dinv) ----------------
__global__ __launch_bounds__(256) void k_ht(const float* __restrict__ h, const float* __restrict__ stats_l,
                                            const float* __restrict__ gamma, const float* __restrict__ beta,
                                            const float* __restrict__ convw,
                                            const float* __restrict__ dinv,
                                            __half* __restrict__ hts16, int l, int N){
  __shared__ float A[CH*CH], c0[CH], sA[CH], sT[CH];
  int t = threadIdx.x;
  if(t < CH){
    const float invN = 1.0f / (float)NNODES;
    float mu  = stats_l[t*SPAD]      * invN;
    float ex2 = stats_l[(CH+t)*SPAD] * invN;
    float var = ex2 - mu*mu;
    float r   = 1.0f / sqrtf(var + BN_EPS);
    float sc  = r * gamma[l*CH+t];
    sA[t] = sc;
    sT[t] = beta[l*CH+t] - mu*sc;
  }
  __syncthreads();
  if(t < CH*CH){
    int ci = t>>3, co = t&7;
    A[t] = sA[ci] * convw[(l*CH+ci)*CH+co];
  }
  if(t < CH){
    float a = 0.f;
    #pragma unroll
    for(int ci=0;ci<CH;ci++) a += sT[ci]*convw[(l*CH+ci)*CH+t];
    c0[t] = a;
  }
  __syncthreads();
  int i = blockIdx.x*blockDim.x + threadIdx.x;
  if(i >= N) return;
  const float4* hp = (const float4*)(h + (size_t)i*CH);
  float4 a = hp[0], b = hp[1];
  float v[CH] = {a.x,a.y,a.z,a.w,b.x,b.y,b.z,b.w};
  float o[CH];
  #pragma unroll
  for(int co=0;co<CH;co++) o[co]=c0[co];
  #pragma unroll
  for(int ci=0;ci<CH;ci++){
    float vv = v[ci];
    #pragma unroll
    for(int co=0;co<CH;co++) o[co] += vv*A[ci*CH+co];
  }
  float dn = dinv[i];
  union { __half hh[CH]; uint4 u; } pk;
  #pragma unroll
  for(int c=0;c<CH;c++) pk.hh[c] = __float2half(o[c]*dn);
  *(uint4*)(hts16 + (size_t)i*CH) = pk.u;
}

// ---------------- src-sorted bucket push, PARTIAL accumulate ----------------
// 2 blocks per bucket (disjoint edge-range halves), 512 threads, 8 lanes/edge.
__global__ __launch_bounds__(512) void k_push(const unsigned int* __restrict__ binned2,
                                              const int* __restrict__ bbase,
                                              const __half* __restrict__ hts16,
                                              int* __restrict__ pacc){
  __shared__ int acc[BSZ*CH];    // 16 KB, fixed-point 2^21
  int bh = blockIdx.x, b = bh>>1, half = bh&1;
  int t = threadIdx.x;
  #pragma unroll
  for(int i=t; i<BSZ*CH; i+=512) acc[i] = 0;
  __syncthreads();
  int s0 = bbase[b], s1 = bbase[b+1];
  int mid = s0 + ((s1 - s0) >> 1);
  int a0 = half ? mid : s0;
  int a1 = half ? s1  : mid;
  int lane8 = t & 7;
  int g = t >> 3;                          // 0..63
  for(int base = a0 + g*4; base < a1; base += 256){
    int m = a1 - base;
    if(m >= 4){
      unsigned p0 = binned2[base], p1 = binned2[base+1], p2 = binned2[base+2], p3 = binned2[base+3];
      float v0 = __half2float(hts16[(size_t)(p0 & 0x3FFFF)*CH + lane8]);
      float v1 = __half2float(hts16[(size_t)(p1 & 0x3FFFF)*CH + lane8]);
      float v2 = __half2float(hts16[(size_t)(p2 & 0x3FFFF)*CH + lane8]);
      float v3 = __half2float(hts16[(size_t)(p3 & 0x3FFFF)*CH + lane8]);
      atomicAdd(&acc[(p0>>18)*CH + lane8], __float2int_rn(v0*FXSCALE));
      atomicAdd(&acc[(p1>>18)*CH + lane8], __float2int_rn(v1*FXSCALE));
      atomicAdd(&acc[(p2>>18)*CH + lane8], __float2int_rn(v2*FXSCALE));
      atomicAdd(&acc[(p3>>18)*CH + lane8], __float2int_rn(v3*FXSCALE));
    } else {
      for(int i=0; i<m; i++){
        unsigned p = binned2[base+i];
        float v = __half2float(hts16[(size_t)(p & 0x3FFFF)*CH + lane8]);
        atomicAdd(&acc[(p>>18)*CH + lane8], __float2int_rn(v*FXSCALE));
      }
    }
  }
  __syncthreads();
  // dump partial: 4096 ints = 1024 int4, 512 threads x 2, coalesced
  int4* dst = (int4*)(pacc + (size_t)bh*BSZ*CH);
  const int4* src = (const int4*)acc;
  dst[t]       = src[t];
  dst[t + 512] = src[t + 512];
}

// ---------------- finalize: combine partials + self loop + residual + ReLU + stats ----------------
// Grid-strided over NFIN blocks: bounds the per-line stats-atomic count at NFIN
// (6250 blocks => 6250 serialized same-line atomics = 153us; NFIN=512 => ~13us).
__global__ __launch_bounds__(256) void k_fin(const int* __restrict__ pacc,
                                             const __half* __restrict__ hts16,
                                             const float* __restrict__ dinv,
                                             const float* __restrict__ convb,
                                             float* __restrict__ h, float* __restrict__ stats_next,
                                             int l, int N){
  int lane8 = threadIdx.x & 7;
  float bl = convb[l*CH + lane8];
  float S = 0.f, Q = 0.f;
  for(int tid = blockIdx.x*256 + threadIdx.x; tid < N*CH; tid += NFIN*256){
    int node = tid >> 3;
    int b  = node >> 9;
    int dl = node & (BSZ-1);
    int a0 = pacc[((size_t)(2*b  )*BSZ + dl)*CH + lane8];
    int a1 = pacc[((size_t)(2*b+1)*BSZ + dl)*CH + lane8];
    float a = (float)(a0 + a1) * FXINV;
    float sv = __half2float(hts16[(size_t)node*CH + lane8]);   // self loop (pre-scaled)
    float hv = h[(size_t)node*CH + lane8];
    float r = hv + bl + dinv[node]*(a + sv);
    float val = fmaxf(r, 0.f);
    h[(size_t)node*CH + lane8] = val;
    S += val; Q += val*val;
  }
  S += __shfl_xor(S, 8);  Q += __shfl_xor(Q, 8);
  S += __shfl_xor(S, 16); Q += __shfl_xor(Q, 16);
  S += __shfl_xor(S, 32); Q += __shfl_xor(Q, 32);
  __shared__ float ls[4][2*CH];
  int wave = threadIdx.x>>6, wl = threadIdx.x&63;
  if(wl < CH){ ls[wave][wl] = S; ls[wave][CH+wl] = Q; }
  __syncthreads();
  if(threadIdx.x < 2*CH){
    float tsum = ls[0][threadIdx.x]+ls[1][threadIdx.x]+ls[2][threadIdx.x]+ls[3][threadIdx.x];
    unsafeAtomicAdd(&stats_next[threadIdx.x*SPAD], tsum);
  }
}

// ---------------- entries: u = xe@W1, v = xe@W2 + hb ----------------
__global__ __launch_bounds__(256) void k_uv(const int* __restrict__ entry, const float* __restrict__ h,
                                            const float* __restrict__ hw, const float* __restrict__ hb,
                                            float* __restrict__ u, float* __restrict__ v){
  __shared__ float w[2*CH*HID];
  __shared__ float b[HID];
  for(int t=threadIdx.x; t<2*CH*HID; t+=256) w[t]=hw[t];
  if(threadIdx.x<HID) b[threadIdx.x]=hb[threadIdx.x];
  __syncthreads();
  int k = blockIdx.x*blockDim.x + threadIdx.x;
  if(k >= NENT) return;
  int node = entry[k];
  const float4* hp = (const float4*)(h + (size_t)node*CH);
  float4 a = hp[0], b4 = hp[1];
  float xe[CH] = {a.x,a.y,a.z,a.w,b4.x,b4.y,b4.z,b4.w};
  #pragma unroll 4
  for(int c=0;c<HID;c++){
    float uu = 0.f, vv = b[c];
    #pragma unroll
    for(int ci=0;ci<CH;ci++){
      uu += xe[ci]*w[ci*HID+c];
      vv += xe[ci]*w[(CH+ci)*HID+c];
    }
    u[(size_t)k*HID+c] = uu;
    v[(size_t)k*HID+c] = vv;
  }
}

// ---------------- pairwise scorer ----------------
__global__ __launch_bounds__(256) void k_pair(const float* __restrict__ u, const float* __restrict__ v,
                                              const float* __restrict__ ow, const float* __restrict__ ob,
                                              float* __restrict__ out){
  __shared__ float us[16][HID+1];
  __shared__ float vs[64][HID+1];
  __shared__ float wo[HID];
  int tid = threadIdx.x;
  int jb = blockIdx.x*64, ib = blockIdx.y*16;
  for(int t=tid; t<16*HID; t+=256) us[t>>5][t&31] = u[(size_t)(ib + (t>>5))*HID + (t&31)];
  for(int t=tid; t<64*HID; t+=256) vs[t>>5][t&31] = v[(size_t)(jb + (t>>5))*HID + (t&31)];
  if(tid<HID) wo[tid]=ow[tid];
  __syncthreads();
  int tx = tid&63, ty = tid>>6;
  float a0=0.f, a1=0.f, a2=0.f, a3=0.f;
  #pragma unroll
  for(int c=0;c<HID;c++){
    float vv = vs[tx][c];
    float w  = wo[c];
    a0 += fmaxf(us[ty   ][c]+vv, 0.f)*w;
    a1 += fmaxf(us[ty+4 ][c]+vv, 0.f)*w;
    a2 += fmaxf(us[ty+8 ][c]+vv, 0.f)*w;
    a3 += fmaxf(us[ty+12][c]+vv, 0.f)*w;
  }
  float o0 = ob[0];
  size_t base = (size_t)ib*2048 + jb + tx;
  out[base + (size_t)(ty   )*2048] = a0+o0;
  out[base + (size_t)(ty+4 )*2048] = a1+o0;
  out[base + (size_t)(ty+8 )*2048] = a2+o0;
  out[base + (size_t)(ty+12)*2048] = a3+o0;
}

extern "C" void kernel_launch(void* const* d_in, const int* in_sizes, int n_in,
                              void* d_out, int out_size, void* d_ws, size_t ws_size,
                              hipStream_t stream){
  const int*   x     = (const int*)d_in[0];
  const int*   ei    = (const int*)d_in[1];
  const int*   entry = (const int*)d_in[2];
  const float* emb   = (const float*)d_in[3];
  const float* gamma = (const float*)d_in[4];
  const float* beta  = (const float*)d_in[5];
  const float* convw = (const float*)d_in[6];
  const float* convb = (const float*)d_in[7];
  const float* hw    = (const float*)d_in[8];
  const float* hb    = (const float*)d_in[9];
  const float* ow    = (const float*)d_in[10];
  const float* ob    = (const float*)d_in[11];
  const int* srcp = ei;
  const int* dstp = ei + NEDGES;

  // workspace (~67 MB; pacc aliases binned, which is dead after k_sub)
  char* ws = (char*)d_ws;
  size_t o = 0;
  auto alloc = [&](size_t bytes){ void* p = ws + o; o += (bytes + 255) & ~(size_t)255; return p; };
  int*      cnt    = (int*)     alloc((size_t)NCHUNK*NBUCK*4);   // 2.44 MB
  int*      total  = (int*)     alloc(NBUCK*4);
  int*      bbase  = (int*)     alloc((NBUCK+1)*4);
  unsigned* binned = (unsigned*)alloc((size_t)NEDGES*4);         // 25.6 MB (dst-bucket runs; dead after k_sub)
  unsigned* binned2= (unsigned*)alloc((size_t)NEDGES*4);         // 25.6 MB (src-sorted runs)
  float*    dinv   = (float*)   alloc(NNODES*4);
  float*    h      = (float*)   alloc((size_t)NNODES*CH*4);
  __half*   hts16  = (__half*)  alloc((size_t)NNODES*CH*2);      // 3.2 MB
  float*    stats  = (float*)   alloc((NCONV+1)*2*CH*SPAD*4);    // padded: one line per channel-stat
  float*    ub     = (float*)   alloc((size_t)NENT*HID*4);
  float*    vb     = (float*)   alloc((size_t)NENT*HID*4);
  int*      pacc   = (int*)binned;                               // 782*4096*4 = 12.8 MB, fits in binned
  (void)ws_size; (void)in_sizes; (void)n_in; (void)out_size;

  // ---- deterministic CSR build + src-bin re-sort ----
  k_chist<<<NCHUNK, 256, 0, stream>>>(dstp, cnt, NEDGES);
  k_cscan<<<NBUCK, 256, 0, stream>>>(cnt, total);
  k_bscan<<<1, 512, 0, stream>>>(total, bbase);
  k_bin  <<<NCHUNK, 512, 0, stream>>>(srcp, dstp, cnt, bbase, binned, NEDGES);
  k_sub  <<<NBUCK*2, 512, 0, stream>>>(binned, bbase, binned2, dinv, NNODES);

  hipMemsetAsync(stats, 0, (NCONV+1)*2*CH*SPAD*sizeof(float), stream);
  k_init_h<<<(NNODES+255)/256, 256, 0, stream>>>(x, emb, h, stats, NNODES);

  for(int l=0; l<NCONV; l++){
    k_ht  <<<(NNODES+255)/256, 256, 0, stream>>>(h, stats + (size_t)l*2*CH*SPAD, gamma, beta, convw,
                                                 dinv, hts16, l, NNODES);
    k_push<<<NBUCK*2, 512, 0, stream>>>(binned2, bbase, hts16, pacc);
    k_fin <<<NFIN, 256, 0, stream>>>(pacc, hts16, dinv, convb, h,
                                     stats + (size_t)(l+1)*2*CH*SPAD, l, NNODES);
  }

  k_uv<<<NENT/256, 256, 0, stream>>>(entry, h, hw, hb, ub, vb);
  dim3 pg(2048/64, 2048/16);
  k_pair<<<pg, 256, 0, stream>>>(ub, vb, ow, ob, (float*)d_out);
}

// Round 17
// 617.683 us; speedup vs baseline: 2.7514x; 1.0028x over previous
//
#include <hip/hip_runtime.h>
#include <hip/hip_fp16.h>

#define NNODES 200000
#define NEDGES 6400000
#define NENT   2048
#define CH     8
#define HID    32
#define NCONV  8
#define BN_EPS 1e-5f

#define BSZ    256                                  // nodes per dst-bucket
#define NBUCK  ((NNODES + BSZ - 1) / BSZ)           // 782
#define SRCB   391                                  // src bins (src>>9)
#define CHUNK  4096
#define NCHUNK ((NEDGES + CHUNK - 1) / CHUNK)       // 1563
#define SPAD   16                                   // stats padding: one 64B line per channel-stat
#define SUBCAP 12288                                // staged edges per bucket (48 KB; run ~8192+-4sig)

#define FXSCALE   2097152.0f                        // 2^21 fixed-point scale for LDS int accumulation
#define FXINV     (1.0f/2097152.0f)

// ---------------- phase A: per-chunk bucket histogram ----------------
__global__ __launch_bounds__(256) void k_chist(const int* __restrict__ dst, int* __restrict__ cnt, int E){
  __shared__ int hist[NBUCK];
  for(int t=threadIdx.x; t<NBUCK; t+=256) hist[t]=0;
  __syncthreads();
  int e0 = blockIdx.x*CHUNK;
  int n = min(CHUNK, E-e0);
  for(int i=threadIdx.x; i<n; i+=256) atomicAdd(&hist[dst[e0+i]>>8], 1);
  __syncthreads();
  for(int t=threadIdx.x; t<NBUCK; t+=256) cnt[(size_t)blockIdx.x*NBUCK + t] = hist[t];
}

// ---------------- phase B1: per-bucket exclusive scan over chunks ----------------
__global__ __launch_bounds__(256) void k_cscan(int* __restrict__ cnt, int* __restrict__ total){
  int b = blockIdx.x;
  __shared__ int sd[256];
  int carry = 0;
  for(int base=0; base<NCHUNK; base+=256){
    int c = base + threadIdx.x;
    int v = (c<NCHUNK) ? cnt[(size_t)c*NBUCK + b] : 0;
    sd[threadIdx.x] = v; __syncthreads();
    #pragma unroll
    for(int o=1; o<256; o<<=1){
      int x = (threadIdx.x>=o) ? sd[threadIdx.x-o] : 0;
      __syncthreads();
      sd[threadIdx.x] += x;
      __syncthreads();
    }
    if(c<NCHUNK) cnt[(size_t)c*NBUCK + b] = carry + sd[threadIdx.x] - v;  // exclusive
    carry += sd[255];
    __syncthreads();
  }
  if(threadIdx.x==0) total[b] = carry;
}

// ---------------- phase B2: bucket base scan (782 bins, 1024 threads) ----------------
__global__ __launch_bounds__(1024) void k_bscan(const int* __restrict__ total, int* __restrict__ bbase){
  __shared__ int sd[1024];
  int t = threadIdx.x;
  int v = (t<NBUCK) ? total[t] : 0;
  sd[t] = v; __syncthreads();
  #pragma unroll
  for(int o=1; o<1024; o<<=1){
    int x = (t>=o) ? sd[t-o] : 0;
    __syncthreads();
    sd[t] += x;
    __syncthreads();
  }
  if(t<NBUCK) bbase[t] = sd[t] - v;
  if(t==1023) bbase[NBUCK] = sd[1023];   // == NEDGES
}

// ---------------- phase C: LDS counting-sort scatter into bucket runs ----------------
// packed edge = (dst_local<<18) | src   (src<2^18, dst_local<256)
__global__ __launch_bounds__(1024) void k_bin(const int* __restrict__ src, const int* __restrict__ dst,
                                              const int* __restrict__ cnt, const int* __restrict__ bbase,
                                              unsigned int* __restrict__ binned, int E){
  __shared__ int hist[NBUCK], excl[NBUCK], cur[NBUCK], base[NBUCK];
  __shared__ unsigned int pin[CHUNK];
  __shared__ unsigned short bk_in[CHUNK];
  __shared__ unsigned int sorted[CHUNK];
  __shared__ unsigned short sbkt[CHUNK];
  __shared__ int sd[1024];
  int c = blockIdx.x;
  int e0 = c*CHUNK, n = min(CHUNK, E-e0);
  for(int t=threadIdx.x; t<NBUCK; t+=1024) hist[t]=0;
  __syncthreads();
  for(int i=threadIdx.x; i<n; i+=1024){
    int s = src[e0+i], d = dst[e0+i];
    int b = d>>8;
    pin[i]   = ((unsigned)(d & (BSZ-1))<<18) | (unsigned)s;
    bk_in[i] = (unsigned short)b;
    atomicAdd(&hist[b], 1);
  }
  __syncthreads();
  int t = threadIdx.x;
  int hv = (t<NBUCK) ? hist[t] : 0;
  sd[t] = hv; __syncthreads();
  #pragma unroll
  for(int o=1; o<1024; o<<=1){
    int x = (t>=o) ? sd[t-o] : 0;
    __syncthreads();
    sd[t] += x;
    __syncthreads();
  }
  if(t<NBUCK){
    int ex = sd[t] - hv;
    excl[t] = ex; cur[t] = ex;
    base[t] = bbase[t] + cnt[(size_t)c*NBUCK + t];
  }
  __syncthreads();
  for(int i=threadIdx.x; i<n; i+=1024){
    int b = bk_in[i];
    int slot = atomicAdd(&cur[b], 1);
    sorted[slot] = pin[i];
    sbkt[slot]   = (unsigned short)b;
  }
  __syncthreads();
  for(int i=threadIdx.x; i<n; i+=1024){
    int b = sbkt[i];
    binned[ base[b] + (i - excl[b]) ] = sorted[i];   // contiguous runs per bucket
  }
}

// ---------------- phase D: per-bucket SRC-BIN sort, LDS-staged coalesced output ----------------
// One block per bucket (run ~8192 <= SUBCAP). Sort run by src>>9 for sequential gathers;
// stage in LDS, write out coalesced. Also emits degree -> dinv.
__global__ __launch_bounds__(512) void k_sub(const unsigned int* __restrict__ binned,
                                             const int* __restrict__ bbase,
                                             unsigned int* __restrict__ binned2,
                                             float* __restrict__ dinv, int N){
  __shared__ int hd[BSZ];        // dst_local degree histogram
  __shared__ int hs[SRCB];       // src-bin histogram
  __shared__ int cur[SRCB];
  __shared__ int sd[512];
  __shared__ unsigned int stage[SUBCAP];   // 48 KB
  int b = blockIdx.x;
  int t = threadIdx.x;
  if(t < BSZ)  hd[t] = 0;
  if(t < SRCB) hs[t] = 0;
  __syncthreads();
  int s0 = bbase[b], s1 = bbase[b+1];
  for(int i=s0+t; i<s1; i+=512){
    unsigned p = binned[i];
    atomicAdd(&hd[p>>18], 1);
    atomicAdd(&hs[(p & 0x3FFFF)>>9], 1);
  }
  __syncthreads();
  if(t < BSZ){
    int node = b*BSZ + t;
    if(node < N) dinv[node] = 1.0f / sqrtf((float)hd[t] + 1.0f);
  }
  // exclusive scan of src-bin histogram (391 <= 512)
  int hv = (t<SRCB) ? hs[t] : 0;
  sd[t] = hv; __syncthreads();
  #pragma unroll
  for(int o=1; o<512; o<<=1){
    int x = (t>=o) ? sd[t-o] : 0;
    __syncthreads();
    sd[t] += x;
    __syncthreads();
  }
  if(t<SRCB) cur[t] = sd[t] - hv;          // stage-relative
  __syncthreads();
  int len = s1 - s0;
  if(len <= SUBCAP){
    for(int i=s0+t; i<s1; i+=512){
      unsigned p = binned[i];
      int slot = atomicAdd(&cur[(p & 0x3FFFF)>>9], 1);
      stage[slot] = p;
    }
    __syncthreads();
    for(int i=t; i<len; i+=512) binned2[s0 + i] = stage[i];   // coalesced
  } else {                                 // degenerate fallback: direct scatter
    for(int i=s0+t; i<s1; i+=512){
      unsigned p = binned[i];
      int slot = atomicAdd(&cur[(p & 0x3FFFF)>>9], 1);
      binned2[s0 + slot] = p;
    }
  }
}

// ---------------- h init: embedding gather + stats[0] (fp32 atomics, padded lines) ----------------
__global__ __launch_bounds__(256) void k_init_h(const int* __restrict__ x, const float* __restrict__ emb,
                                                float* __restrict__ h, float* __restrict__ stats0, int N){
  int i = blockIdx.x*256 + threadIdx.x;
  float v[CH];
  #pragma unroll
  for(int c=0;c<CH;c++) v[c]=0.f;
  if(i < N){
    int tt = x[i];
    const float4* ep = (const float4*)(emb + (size_t)tt*CH);
    float4 a = ep[0], b = ep[1];
    float4* hp = (float4*)(h + (size_t)i*CH);
    hp[0] = a; hp[1] = b;
    v[0]=a.x; v[1]=a.y; v[2]=a.z; v[3]=a.w; v[4]=b.x; v[5]=b.y; v[6]=b.z; v[7]=b.w;
  }
  float s[CH], q[CH];
  #pragma unroll
  for(int c=0;c<CH;c++){ s[c]=v[c]; q[c]=v[c]*v[c]; }
  #pragma unroll
  for(int off=32; off>0; off>>=1){
    #pragma unroll
    for(int c=0;c<CH;c++){ s[c]+=__shfl_down(s[c],off); q[c]+=__shfl_down(q[c],off); }
  }
  __shared__ float ls[4][2*CH];
  int wave = threadIdx.x>>6, lane = threadIdx.x&63;
  if(lane==0){
    #pragma unroll
    for(int c=0;c<CH;c++){ ls[wave][c]=s[c]; ls[wave][CH+c]=q[c]; }
  }
  __syncthreads();
  if(threadIdx.x < 2*CH){
    float tsum = ls[0][threadIdx.x]+ls[1][threadIdx.x]+ls[2][threadIdx.x]+ls[3][threadIdx.x];
    unsafeAtomicAdd(&stats0[threadIdx.x*SPAD], tsum);
  }
}

// ---------------- per-node transform: fold BN in-block, hts16 = fp16((h@A+c0)*dinv) ----------------
__global__ __launch_bounds__(256) void k_ht(const float* __restrict__ h, const float* __restrict__ stats_l,
                                            const float* __restrict__ gamma, const float* __restrict__ beta,
                                            const float* __restrict__ convw,
                                            const float* __restrict__ dinv,
                                            __half* __restrict__ hts16, int l, int N){
  __shared__ float A[CH*CH], c0[CH], sA[CH], sT[CH];
  int t = threadIdx.x;
  if(t < CH){
    const float invN = 1.0f / (float)NNODES;
    float mu  = stats_l[t*SPAD]      * invN;
    float ex2 = stats_l[(CH+t)*SPAD] * invN;
    float var = ex2 - mu*mu;
    float r   = 1.0f / sqrtf(var + BN_EPS);
    float sc  = r * gamma[l*CH+t];
    sA[t] = sc;
    sT[t] = beta[l*CH+t] - mu*sc;
  }
  __syncthreads();
  if(t < CH*CH){
    int ci = t>>3, co = t&7;
    A[t] = sA[ci] * convw[(l*CH+ci)*CH+co];
  }
  if(t < CH){
    float a = 0.f;
    #pragma unroll
    for(int ci=0;ci<CH;ci++) a += sT[ci]*convw[(l*CH+ci)*CH+t];
    c0[t] = a;
  }
  __syncthreads();
  int i = blockIdx.x*blockDim.x + threadIdx.x;
  if(i >= N) return;
  const float4* hp = (const float4*)(h + (size_t)i*CH);
  float4 a = hp[0], b = hp[1];
  float v[CH] = {a.x,a.y,a.z,a.w,b.x,b.y,b.z,b.w};
  float o[CH];
  #pragma unroll
  for(int co=0;co<CH;co++) o[co]=c0[co];
  #pragma unroll
  for(int ci=0;ci<CH;ci++){
    float vv = v[ci];
    #pragma unroll
    for(int co=0;co<CH;co++) o[co] += vv*A[ci*CH+co];
  }
  float dn = dinv[i];
  union { __half hh[CH]; uint4 u; } pk;
  #pragma unroll
  for(int c=0;c<CH;c++) pk.hh[c] = __float2half(o[c]*dn);
  *(uint4*)(hts16 + (size_t)i*CH) = pk.u;
}

// ---------------- src-sorted bucket push + FUSED finalize ----------------
// One block per 256-node dst-bucket (782 blocks -> 3.05/CU, all CUs), 512 threads.
// 8 lanes/edge; fixed-point int LDS acc (native ds_add). Block exclusively owns its
// dsts -> epilogue does self-loop + residual + ReLU + BN-stats in-place (no pacc/k_fin).
__global__ __launch_bounds__(512) void k_push(const unsigned int* __restrict__ binned2,
                                              const int* __restrict__ bbase,
                                              const __half* __restrict__ hts16,
                                              const float* __restrict__ dinv,
                                              const float* __restrict__ convb,
                                              float* __restrict__ h, float* __restrict__ stats_next,
                                              int l, int N){
  __shared__ int acc[BSZ*CH];    // 8 KB, fixed-point 2^21
  int b = blockIdx.x, t = threadIdx.x;
  #pragma unroll
  for(int i=t; i<BSZ*CH; i+=512) acc[i] = 0;
  __syncthreads();
  int s0 = bbase[b], s1 = bbase[b+1];
  int lane8 = t & 7;
  int g = t >> 3;                          // 0..63
  for(int base = s0 + g*4; base < s1; base += 256){
    int m = s1 - base;
    if(m >= 4){
      unsigned p0 = binned2[base], p1 = binned2[base+1], p2 = binned2[base+2], p3 = binned2[base+3];
      float v0 = __half2float(hts16[(size_t)(p0 & 0x3FFFF)*CH + lane8]);
      float v1 = __half2float(hts16[(size_t)(p1 & 0x3FFFF)*CH + lane8]);
      float v2 = __half2float(hts16[(size_t)(p2 & 0x3FFFF)*CH + lane8]);
      float v3 = __half2float(hts16[(size_t)(p3 & 0x3FFFF)*CH + lane8]);
      atomicAdd(&acc[(p0>>18)*CH + lane8], __float2int_rn(v0*FXSCALE));
      atomicAdd(&acc[(p1>>18)*CH + lane8], __float2int_rn(v1*FXSCALE));
      atomicAdd(&acc[(p2>>18)*CH + lane8], __float2int_rn(v2*FXSCALE));
      atomicAdd(&acc[(p3>>18)*CH + lane8], __float2int_rn(v3*FXSCALE));
    } else {
      for(int i=0; i<m; i++){
        unsigned p = binned2[base+i];
        float v = __half2float(hts16[(size_t)(p & 0x3FFFF)*CH + lane8]);
        atomicAdd(&acc[(p>>18)*CH + lane8], __float2int_rn(v*FXSCALE));
      }
    }
  }
  __syncthreads();
  // epilogue: thread t<256 owns node b*256+t (this block exclusively owns these dsts)
  float vv[CH];
  #pragma unroll
  for(int c=0;c<CH;c++) vv[c]=0.f;
  int node = b*BSZ + t;
  if(t < BSZ && node < N){
    const int4* ar = (const int4*)(acc + t*CH);
    int4 a0 = ar[0], a1 = ar[1];
    float av[CH] = {(float)a0.x*FXINV,(float)a0.y*FXINV,(float)a0.z*FXINV,(float)a0.w*FXINV,
                    (float)a1.x*FXINV,(float)a1.y*FXINV,(float)a1.z*FXINV,(float)a1.w*FXINV};
    uint4 su = *(const uint4*)(hts16 + (size_t)node*CH);    // self loop (pre-scaled)
    const __half2* sp = (const __half2*)&su;
    float sv[CH];
    #pragma unroll
    for(int j=0;j<4;j++){
      float2 f = __half22float2(sp[j]);
      sv[2*j] = f.x; sv[2*j+1] = f.y;
    }
    const float4* hp = (const float4*)(h + (size_t)node*CH);
    float4 h0 = hp[0], h1 = hp[1];
    float hv2[CH] = {h0.x,h0.y,h0.z,h0.w,h1.x,h1.y,h1.z,h1.w};
    float dn = dinv[node];
    #pragma unroll
    for(int c=0;c<CH;c++){
      float r = hv2[c] + convb[l*CH + c] + dn*(av[c] + sv[c]);
      vv[c] = fmaxf(r, 0.f);
    }
    float4* hw4 = (float4*)(h + (size_t)node*CH);
    hw4[0] = make_float4(vv[0],vv[1],vv[2],vv[3]);
    hw4[1] = make_float4(vv[4],vv[5],vv[6],vv[7]);
  }
  // next-layer BN stats
  float s[CH], q[CH];
  #pragma unroll
  for(int c=0;c<CH;c++){ s[c]=vv[c]; q[c]=vv[c]*vv[c]; }
  #pragma unroll
  for(int off=32; off>0; off>>=1){
    #pragma unroll
    for(int c=0;c<CH;c++){ s[c]+=__shfl_down(s[c],off); q[c]+=__shfl_down(q[c],off); }
  }
  __shared__ float ls[8][2*CH];
  int wave = t>>6, lane = t&63;
  if(lane==0){
    #pragma unroll
    for(int c=0;c<CH;c++){ ls[wave][c]=s[c]; ls[wave][CH+c]=q[c]; }
  }
  __syncthreads();
  if(t < 2*CH){
    float tot = 0.f;
    #pragma unroll
    for(int w=0; w<8; w++) tot += ls[w][t];
    unsafeAtomicAdd(&stats_next[t*SPAD], tot);
  }
}

// ---------------- entries: u = xe@W1, v = xe@W2 + hb ----------------
__global__ __launch_bounds__(256) void k_uv(const int* __restrict__ entry, const float* __restrict__ h,
                                            const float* __restrict__ hw, const float* __restrict__ hb,
                                            float* __restrict__ u, float* __restrict__ v){
  __shared__ float w[2*CH*HID];
  __shared__ float b[HID];
  for(int t=threadIdx.x; t<2*CH*HID; t+=256) w[t]=hw[t];
  if(threadIdx.x<HID) b[threadIdx.x]=hb[threadIdx.x];
  __syncthreads();
  int k = blockIdx.x*blockDim.x + threadIdx.x;
  if(k >= NENT) return;
  int node = entry[k];
  const float4* hp = (const float4*)(h + (size_t)node*CH);
  float4 a = hp[0], b4 = hp[1];
  float xe[CH] = {a.x,a.y,a.z,a.w,b4.x,b4.y,b4.z,b4.w};
  #pragma unroll 4
  for(int c=0;c<HID;c++){
    float uu = 0.f, vv = b[c];
    #pragma unroll
    for(int ci=0;ci<CH;ci++){
      uu += xe[ci]*w[ci*HID+c];
      vv += xe[ci]*w[(CH+ci)*HID+c];
    }
    u[(size_t)k*HID+c] = uu;
    v[(size_t)k*HID+c] = vv;
  }
}

// ---------------- pairwise scorer ----------------
__global__ __launch_bounds__(256) void k_pair(const float* __restrict__ u, const float* __restrict__ v,
                                              const float* __restrict__ ow, const float* __restrict__ ob,
                                              float* __restrict__ out){
  __shared__ float us[16][HID+1];
  __shared__ float vs[64][HID+1];
  __shared__ float wo[HID];
  int tid = threadIdx.x;
  int jb = blockIdx.x*64, ib = blockIdx.y*16;
  for(int t=tid; t<16*HID; t+=256) us[t>>5][t&31] = u[(size_t)(ib + (t>>5))*HID + (t&31)];
  for(int t=tid; t<64*HID; t+=256) vs[t>>5][t&31] = v[(size_t)(jb + (t>>5))*HID + (t&31)];
  if(tid<HID) wo[tid]=ow[tid];
  __syncthreads();
  int tx = tid&63, ty = tid>>6;
  float a0=0.f, a1=0.f, a2=0.f, a3=0.f;
  #pragma unroll
  for(int c=0;c<HID;c++){
    float vv = vs[tx][c];
    float w  = wo[c];
    a0 += fmaxf(us[ty   ][c]+vv, 0.f)*w;
    a1 += fmaxf(us[ty+4 ][c]+vv, 0.f)*w;
    a2 += fmaxf(us[ty+8 ][c]+vv, 0.f)*w;
    a3 += fmaxf(us[ty+12][c]+vv, 0.f)*w;
  }
  float o0 = ob[0];
  size_t base = (size_t)ib*2048 + jb + tx;
  out[base + (size_t)(ty   )*2048] = a0+o0;
  out[base + (size_t)(ty+4 )*2048] = a1+o0;
  out[base + (size_t)(ty+8 )*2048] = a2+o0;
  out[base + (size_t)(ty+12)*2048] = a3+o0;
}

extern "C" void kernel_launch(void* const* d_in, const int* in_sizes, int n_in,
                              void* d_out, int out_size, void* d_ws, size_t ws_size,
                              hipStream_t stream){
  const int*   x     = (const int*)d_in[0];
  const int*   ei    = (const int*)d_in[1];
  const int*   entry = (const int*)d_in[2];
  const float* emb   = (const float*)d_in[3];
  const float* gamma = (const float*)d_in[4];
  const float* beta  = (const float*)d_in[5];
  const float* convw = (const float*)d_in[6];
  const float* convb = (const float*)d_in[7];
  const float* hw    = (const float*)d_in[8];
  const float* hb    = (const float*)d_in[9];
  const float* ow    = (const float*)d_in[10];
  const float* ob    = (const float*)d_in[11];
  const int* srcp = ei;
  const int* dstp = ei + NEDGES;

  // workspace (~70 MB)
  char* ws = (char*)d_ws;
  size_t o = 0;
  auto alloc = [&](size_t bytes){ void* p = ws + o; o += (bytes + 255) & ~(size_t)255; return p; };
  int*      cnt    = (int*)     alloc((size_t)NCHUNK*NBUCK*4);   // 4.89 MB
  int*      total  = (int*)     alloc(NBUCK*4);
  int*      bbase  = (int*)     alloc((NBUCK+1)*4);
  unsigned* binned = (unsigned*)alloc((size_t)NEDGES*4);         // 25.6 MB (dst-bucket runs)
  unsigned* binned2= (unsigned*)alloc((size_t)NEDGES*4);         // 25.6 MB (src-sorted runs)
  float*    dinv   = (float*)   alloc(NNODES*4);
  float*    h      = (float*)   alloc((size_t)NNODES*CH*4);
  __half*   hts16  = (__half*)  alloc((size_t)NNODES*CH*2);      // 3.2 MB
  float*    stats  = (float*)   alloc((NCONV+1)*2*CH*SPAD*4);    // padded: one line per channel-stat
  float*    ub     = (float*)   alloc((size_t)NENT*HID*4);
  float*    vb     = (float*)   alloc((size_t)NENT*HID*4);
  (void)ws_size; (void)in_sizes; (void)n_in; (void)out_size;

  // ---- deterministic CSR build + src-bin re-sort ----
  k_chist<<<NCHUNK, 256, 0, stream>>>(dstp, cnt, NEDGES);
  k_cscan<<<NBUCK, 256, 0, stream>>>(cnt, total);
  k_bscan<<<1, 1024, 0, stream>>>(total, bbase);
  k_bin  <<<NCHUNK, 1024, 0, stream>>>(srcp, dstp, cnt, bbase, binned, NEDGES);
  k_sub  <<<NBUCK, 512, 0, stream>>>(binned, bbase, binned2, dinv, NNODES);

  hipMemsetAsync(stats, 0, (NCONV+1)*2*CH*SPAD*sizeof(float), stream);
  k_init_h<<<(NNODES+255)/256, 256, 0, stream>>>(x, emb, h, stats, NNODES);

  for(int l=0; l<NCONV; l++){
    k_ht  <<<(NNODES+255)/256, 256, 0, stream>>>(h, stats + (size_t)l*2*CH*SPAD, gamma, beta, convw,
                                                 dinv, hts16, l, NNODES);
    k_push<<<NBUCK, 512, 0, stream>>>(binned2, bbase, hts16, dinv, convb, h,
                                      stats + (size_t)(l+1)*2*CH*SPAD, l, NNODES);
  }

  k_uv<<<NENT/256, 256, 0, stream>>>(entry, h, hw, hb, ub, vb);
  dim3 pg(2048/64, 2048/16);
  k_pair<<<pg, 256, 0, stream>>>(ub, vb, ow, ob, (float*)d_out);
}

// Round 18
// 495.273 us; speedup vs baseline: 3.4315x; 1.2472x over previous
//
#include <hip/hip_runtime.h>
#include <hip/hip_fp16.h>

#define NNODES 200000
#define NEDGES 6400000
#define NENT   2048
#define CH     8
#define HID    32
#define NCONV  8
#define BN_EPS 1e-5f

#define BSZ    196                                  // nodes per dst-bucket
#define NBUCK  1024                                 // 1024 buckets -> exactly 4 blocks/CU
#define SRCB   391                                  // src bins (src>>9)
#define CHUNK  4096
#define NCHUNK ((NEDGES + CHUNK - 1) / CHUNK)       // 1563
#define SPAD   16                                   // one 64B line per stat-copy
#define SCOP   16                                   // stat copies (bounds same-line atomic serialization)
#define SUBCAP 8192                                 // staged edges per bucket (32 KB; run ~6272)

#define FXSCALE   2097152.0f                        // 2^21 fixed-point scale for LDS int accumulation
#define FXINV     (1.0f/2097152.0f)

// stats slot layout: [stat t (0..15)][copy c (0..15)] each on its own 64B line
#define SSLOT  (2*CH*SCOP*SPAD)                     // floats per layer slot (4096)

__device__ __forceinline__ int bucket_of(int d){ return (int)((unsigned)d / 196u); }

// ---------------- phase A: per-chunk bucket histogram ----------------
__global__ __launch_bounds__(256) void k_chist(const int* __restrict__ dst, int* __restrict__ cnt, int E){
  __shared__ int hist[NBUCK];
  for(int t=threadIdx.x; t<NBUCK; t+=256) hist[t]=0;
  __syncthreads();
  int e0 = blockIdx.x*CHUNK;
  int n = min(CHUNK, E-e0);
  for(int i=threadIdx.x; i<n; i+=256) atomicAdd(&hist[bucket_of(dst[e0+i])], 1);
  __syncthreads();
  for(int t=threadIdx.x; t<NBUCK; t+=256) cnt[(size_t)blockIdx.x*NBUCK + t] = hist[t];
}

// ---------------- phase B1: per-bucket exclusive scan over chunks ----------------
__global__ __launch_bounds__(256) void k_cscan(int* __restrict__ cnt, int* __restrict__ total){
  int b = blockIdx.x;
  __shared__ int sd[256];
  int carry = 0;
  for(int base=0; base<NCHUNK; base+=256){
    int c = base + threadIdx.x;
    int v = (c<NCHUNK) ? cnt[(size_t)c*NBUCK + b] : 0;
    sd[threadIdx.x] = v; __syncthreads();
    #pragma unroll
    for(int o=1; o<256; o<<=1){
      int x = (threadIdx.x>=o) ? sd[threadIdx.x-o] : 0;
      __syncthreads();
      sd[threadIdx.x] += x;
      __syncthreads();
    }
    if(c<NCHUNK) cnt[(size_t)c*NBUCK + b] = carry + sd[threadIdx.x] - v;  // exclusive
    carry += sd[255];
    __syncthreads();
  }
  if(threadIdx.x==0) total[b] = carry;
}

// ---------------- phase B2: bucket base scan (1024 bins, 1024 threads) ----------------
__global__ __launch_bounds__(1024) void k_bscan(const int* __restrict__ total, int* __restrict__ bbase){
  __shared__ int sd[1024];
  int t = threadIdx.x;
  int v = total[t];
  sd[t] = v; __syncthreads();
  #pragma unroll
  for(int o=1; o<1024; o<<=1){
    int x = (t>=o) ? sd[t-o] : 0;
    __syncthreads();
    sd[t] += x;
    __syncthreads();
  }
  bbase[t] = sd[t] - v;
  if(t==1023) bbase[NBUCK] = sd[1023];   // == NEDGES
}

// ---------------- phase C: LDS counting-sort scatter into bucket runs ----------------
// packed edge = (dst_local<<18) | src   (src<2^18, dst_local<196)
__global__ __launch_bounds__(1024) void k_bin(const int* __restrict__ src, const int* __restrict__ dst,
                                              const int* __restrict__ cnt, const int* __restrict__ bbase,
                                              unsigned int* __restrict__ binned, int E){
  __shared__ int hist[NBUCK], excl[NBUCK], cur[NBUCK], base[NBUCK];
  __shared__ unsigned int pin[CHUNK];
  __shared__ unsigned short bk_in[CHUNK];
  __shared__ unsigned int sorted[CHUNK];
  __shared__ unsigned short sbkt[CHUNK];
  __shared__ int sd[1024];
  int c = blockIdx.x;
  int e0 = c*CHUNK, n = min(CHUNK, E-e0);
  int t = threadIdx.x;
  hist[t]=0;
  __syncthreads();
  for(int i=t; i<n; i+=1024){
    int s = src[e0+i], d = dst[e0+i];
    int b = bucket_of(d);
    pin[i]   = ((unsigned)(d - b*BSZ)<<18) | (unsigned)s;
    bk_in[i] = (unsigned short)b;
    atomicAdd(&hist[b], 1);
  }
  __syncthreads();
  int hv = hist[t];
  sd[t] = hv; __syncthreads();
  #pragma unroll
  for(int o=1; o<1024; o<<=1){
    int x = (t>=o) ? sd[t-o] : 0;
    __syncthreads();
    sd[t] += x;
    __syncthreads();
  }
  {
    int ex = sd[t] - hv;
    excl[t] = ex; cur[t] = ex;
    base[t] = bbase[t] + cnt[(size_t)c*NBUCK + t];
  }
  __syncthreads();
  for(int i=t; i<n; i+=1024){
    int b = bk_in[i];
    int slot = atomicAdd(&cur[b], 1);
    sorted[slot] = pin[i];
    sbkt[slot]   = (unsigned short)b;
  }
  __syncthreads();
  for(int i=t; i<n; i+=1024){
    int b = sbkt[i];
    binned[ base[b] + (i - excl[b]) ] = sorted[i];   // contiguous runs per bucket
  }
}

// ---------------- phase D: per-bucket SRC-BIN sort, LDS-staged coalesced output ----------------
// One block per bucket (run ~6272 <= SUBCAP). Sorts run by src>>9 for gather locality;
// stages in LDS, writes out coalesced. Also emits degree -> dinv.
__global__ __launch_bounds__(512) void k_sub(const unsigned int* __restrict__ binned,
                                             const int* __restrict__ bbase,
                                             unsigned int* __restrict__ binned2,
                                             float* __restrict__ dinv, int N){
  __shared__ int hd[BSZ];        // dst_local degree histogram
  __shared__ int hs[SRCB];       // src-bin histogram
  __shared__ int cur[SRCB];
  __shared__ int sd[512];
  __shared__ unsigned int stage[SUBCAP];   // 32 KB
  int b = blockIdx.x;
  int t = threadIdx.x;
  if(t < BSZ)  hd[t] = 0;
  if(t < SRCB) hs[t] = 0;
  __syncthreads();
  int s0 = bbase[b], s1 = bbase[b+1];
  for(int i=s0+t; i<s1; i+=512){
    unsigned p = binned[i];
    atomicAdd(&hd[p>>18], 1);
    atomicAdd(&hs[(p & 0x3FFFF)>>9], 1);
  }
  __syncthreads();
  if(t < BSZ){
    int node = b*BSZ + t;
    if(node < N) dinv[node] = 1.0f / sqrtf((float)hd[t] + 1.0f);
  }
  // exclusive scan of src-bin histogram (391 <= 512)
  int hv = (t<SRCB) ? hs[t] : 0;
  sd[t] = hv; __syncthreads();
  #pragma unroll
  for(int o=1; o<512; o<<=1){
    int x = (t>=o) ? sd[t-o] : 0;
    __syncthreads();
    sd[t] += x;
    __syncthreads();
  }
  if(t<SRCB) cur[t] = sd[t] - hv;          // stage-relative
  __syncthreads();
  int len = s1 - s0;
  if(len <= SUBCAP){
    for(int i=s0+t; i<s1; i+=512){
      unsigned p = binned[i];
      int slot = atomicAdd(&cur[(p & 0x3FFFF)>>9], 1);
      stage[slot] = p;
    }
    __syncthreads();
    for(int i=t; i<len; i+=512) binned2[s0 + i] = stage[i];   // coalesced
  } else {                                 // degenerate fallback: direct scatter
    for(int i=s0+t; i<s1; i+=512){
      unsigned p = binned[i];
      int slot = atomicAdd(&cur[(p & 0x3FFFF)>>9], 1);
      binned2[s0 + slot] = p;
    }
  }
}

// ---------------- h init: embedding gather + stats[0] (multi-copy fp32 atomics) ----------------
__global__ __launch_bounds__(256) void k_init_h(const int* __restrict__ x, const float* __restrict__ emb,
                                                float* __restrict__ h, float* __restrict__ stats0, int N){
  int i = blockIdx.x*256 + threadIdx.x;
  float v[CH];
  #pragma unroll
  for(int c=0;c<CH;c++) v[c]=0.f;
  if(i < N){
    int tt = x[i];
    const float4* ep = (const float4*)(emb + (size_t)tt*CH);
    float4 a = ep[0], b = ep[1];
    float4* hp = (float4*)(h + (size_t)i*CH);
    hp[0] = a; hp[1] = b;
    v[0]=a.x; v[1]=a.y; v[2]=a.z; v[3]=a.w; v[4]=b.x; v[5]=b.y; v[6]=b.z; v[7]=b.w;
  }
  float s[CH], q[CH];
  #pragma unroll
  for(int c=0;c<CH;c++){ s[c]=v[c]; q[c]=v[c]*v[c]; }
  #pragma unroll
  for(int off=32; off>0; off>>=1){
    #pragma unroll
    for(int c=0;c<CH;c++){ s[c]+=__shfl_down(s[c],off); q[c]+=__shfl_down(q[c],off); }
  }
  __shared__ float ls[4][2*CH];
  int wave = threadIdx.x>>6, lane = threadIdx.x&63;
  if(lane==0){
    #pragma unroll
    for(int c=0;c<CH;c++){ ls[wave][c]=s[c]; ls[wave][CH+c]=q[c]; }
  }
  __syncthreads();
  if(threadIdx.x < 2*CH){
    float tsum = ls[0][threadIdx.x]+ls[1][threadIdx.x]+ls[2][threadIdx.x]+ls[3][threadIdx.x];
    unsafeAtomicAdd(&stats0[(threadIdx.x*SCOP + (blockIdx.x & (SCOP-1)))*SPAD], tsum);
  }
}

// ---------------- per-node transform: reduce stat copies, fold BN, hts16 = fp16((h@A+c0)*dinv) ----------------
__global__ __launch_bounds__(256) void k_ht(const float* __restrict__ h, const float* __restrict__ stats_l,
                                            const float* __restrict__ gamma, const float* __restrict__ beta,
                                            const float* __restrict__ convw,
                                            const float* __restrict__ dinv,
                                            __half* __restrict__ hts16, int l, int N){
  __shared__ float A[CH*CH], c0[CH], sA[CH], sT[CH];
  int t = threadIdx.x;
  if(t < CH){
    float mu = 0.f, ex2 = 0.f;
    #pragma unroll
    for(int c=0;c<SCOP;c++){
      mu  += stats_l[((t   )*SCOP + c)*SPAD];
      ex2 += stats_l[((CH+t)*SCOP + c)*SPAD];
    }
    const float invN = 1.0f / (float)NNODES;
    mu *= invN; ex2 *= invN;
    float var = ex2 - mu*mu;
    float r   = 1.0f / sqrtf(var + BN_EPS);
    float sc  = r * gamma[l*CH+t];
    sA[t] = sc;
    sT[t] = beta[l*CH+t] - mu*sc;
  }
  __syncthreads();
  if(t < CH*CH){
    int ci = t>>3, co = t&7;
    A[t] = sA[ci] * convw[(l*CH+ci)*CH+co];
  }
  if(t < CH){
    float a = 0.f;
    #pragma unroll
    for(int ci=0;ci<CH;ci++) a += sT[ci]*convw[(l*CH+ci)*CH+t];
    c0[t] = a;
  }
  __syncthreads();
  int i = blockIdx.x*blockDim.x + threadIdx.x;
  if(i >= N) return;
  const float4* hp = (const float4*)(h + (size_t)i*CH);
  float4 a = hp[0], b = hp[1];
  float v[CH] = {a.x,a.y,a.z,a.w,b.x,b.y,b.z,b.w};
  float o[CH];
  #pragma unroll
  for(int co=0;co<CH;co++) o[co]=c0[co];
  #pragma unroll
  for(int ci=0;ci<CH;ci++){
    float vv = v[ci];
    #pragma unroll
    for(int co=0;co<CH;co++) o[co] += vv*A[ci*CH+co];
  }
  float dn = dinv[i];
  union { __half hh[CH]; uint4 u; } pk;
  #pragma unroll
  for(int c=0;c<CH;c++) pk.hh[c] = __float2half(o[c]*dn);
  *(uint4*)(hts16 + (size_t)i*CH) = pk.u;
}

// ---------------- src-sorted bucket push + FUSED finalize ----------------
// One block per 196-node dst-bucket: 1024 blocks = exactly 4/CU (balanced max-CU load).
// 512 threads, 8 lanes/edge; fixed-point int LDS acc (native ds_add). Block exclusively
// owns its dsts -> fused self-loop + residual + ReLU + multi-copy BN-stats.
__global__ __launch_bounds__(512) void k_push(const unsigned int* __restrict__ binned2,
                                              const int* __restrict__ bbase,
                                              const __half* __restrict__ hts16,
                                              const float* __restrict__ dinv,
                                              const float* __restrict__ convb,
                                              float* __restrict__ h, float* __restrict__ stats_next,
                                              int l, int N){
  __shared__ int acc[BSZ*CH];    // 6.1 KB, fixed-point 2^21
  int b = blockIdx.x, t = threadIdx.x;
  for(int i=t; i<BSZ*CH; i+=512) acc[i] = 0;
  __syncthreads();
  int s0 = bbase[b], s1 = bbase[b+1];
  int lane8 = t & 7;
  int g = t >> 3;                          // 0..63
  for(int base = s0 + g*4; base < s1; base += 256){
    int m = s1 - base;
    if(m >= 4){
      unsigned p0 = binned2[base], p1 = binned2[base+1], p2 = binned2[base+2], p3 = binned2[base+3];
      float v0 = __half2float(hts16[(size_t)(p0 & 0x3FFFF)*CH + lane8]);
      float v1 = __half2float(hts16[(size_t)(p1 & 0x3FFFF)*CH + lane8]);
      float v2 = __half2float(hts16[(size_t)(p2 & 0x3FFFF)*CH + lane8]);
      float v3 = __half2float(hts16[(size_t)(p3 & 0x3FFFF)*CH + lane8]);
      atomicAdd(&acc[(p0>>18)*CH + lane8], __float2int_rn(v0*FXSCALE));
      atomicAdd(&acc[(p1>>18)*CH + lane8], __float2int_rn(v1*FXSCALE));
      atomicAdd(&acc[(p2>>18)*CH + lane8], __float2int_rn(v2*FXSCALE));
      atomicAdd(&acc[(p3>>18)*CH + lane8], __float2int_rn(v3*FXSCALE));
    } else {
      for(int i=0; i<m; i++){
        unsigned p = binned2[base+i];
        float v = __half2float(hts16[(size_t)(p & 0x3FFFF)*CH + lane8]);
        atomicAdd(&acc[(p>>18)*CH + lane8], __float2int_rn(v*FXSCALE));
      }
    }
  }
  __syncthreads();
  // epilogue: thread t<BSZ owns node b*BSZ+t (this block exclusively owns these dsts)
  float vv[CH];
  #pragma unroll
  for(int c=0;c<CH;c++) vv[c]=0.f;
  int node = b*BSZ + t;
  if(t < BSZ && node < N){
    const int4* ar = (const int4*)(acc + t*CH);
    int4 a0 = ar[0], a1 = ar[1];
    float av[CH] = {(float)a0.x*FXINV,(float)a0.y*FXINV,(float)a0.z*FXINV,(float)a0.w*FXINV,
                    (float)a1.x*FXINV,(float)a1.y*FXINV,(float)a1.z*FXINV,(float)a1.w*FXINV};
    uint4 su = *(const uint4*)(hts16 + (size_t)node*CH);    // self loop (pre-scaled)
    const __half2* sp = (const __half2*)&su;
    float sv[CH];
    #pragma unroll
    for(int j=0;j<4;j++){
      float2 f = __half22float2(sp[j]);
      sv[2*j] = f.x; sv[2*j+1] = f.y;
    }
    const float4* hp = (const float4*)(h + (size_t)node*CH);
    float4 h0 = hp[0], h1 = hp[1];
    float hv2[CH] = {h0.x,h0.y,h0.z,h0.w,h1.x,h1.y,h1.z,h1.w};
    float dn = dinv[node];
    #pragma unroll
    for(int c=0;c<CH;c++){
      float r = hv2[c] + convb[l*CH + c] + dn*(av[c] + sv[c]);
      vv[c] = fmaxf(r, 0.f);
    }
    float4* hw4 = (float4*)(h + (size_t)node*CH);
    hw4[0] = make_float4(vv[0],vv[1],vv[2],vv[3]);
    hw4[1] = make_float4(vv[4],vv[5],vv[6],vv[7]);
  }
  // next-layer BN stats (multi-copy atomics: copy = b & 15)
  float s[CH], q[CH];
  #pragma unroll
  for(int c=0;c<CH;c++){ s[c]=vv[c]; q[c]=vv[c]*vv[c]; }
  #pragma unroll
  for(int off=32; off>0; off>>=1){
    #pragma unroll
    for(int c=0;c<CH;c++){ s[c]+=__shfl_down(s[c],off); q[c]+=__shfl_down(q[c],off); }
  }
  __shared__ float ls[8][2*CH];
  int wave = t>>6, lane = t&63;
  if(lane==0){
    #pragma unroll
    for(int c=0;c<CH;c++){ ls[wave][c]=s[c]; ls[wave][CH+c]=q[c]; }
  }
  __syncthreads();
  if(t < 2*CH){
    float tot = 0.f;
    #pragma unroll
    for(int w=0; w<8; w++) tot += ls[w][t];
    unsafeAtomicAdd(&stats_next[(t*SCOP + (b & (SCOP-1)))*SPAD], tot);
  }
}

// ---------------- entries: u = xe@W1, v = xe@W2 + hb ----------------
__global__ __launch_bounds__(256) void k_uv(const int* __restrict__ entry, const float* __restrict__ h,
                                            const float* __restrict__ hw, const float* __restrict__ hb,
                                            float* __restrict__ u, float* __restrict__ v){
  __shared__ float w[2*CH*HID];
  __shared__ float b[HID];
  for(int t=threadIdx.x; t<2*CH*HID; t+=256) w[t]=hw[t];
  if(threadIdx.x<HID) b[threadIdx.x]=hb[threadIdx.x];
  __syncthreads();
  int k = blockIdx.x*blockDim.x + threadIdx.x;
  if(k >= NENT) return;
  int node = entry[k];
  const float4* hp = (const float4*)(h + (size_t)node*CH);
  float4 a = hp[0], b4 = hp[1];
  float xe[CH] = {a.x,a.y,a.z,a.w,b4.x,b4.y,b4.z,b4.w};
  #pragma unroll 4
  for(int c=0;c<HID;c++){
    float uu = 0.f, vv = b[c];
    #pragma unroll
    for(int ci=0;ci<CH;ci++){
      uu += xe[ci]*w[ci*HID+c];
      vv += xe[ci]*w[(CH+ci)*HID+c];
    }
    u[(size_t)k*HID+c] = uu;
    v[(size_t)k*HID+c] = vv;
  }
}

// ---------------- pairwise scorer ----------------
__global__ __launch_bounds__(256) void k_pair(const float* __restrict__ u, const float* __restrict__ v,
                                              const float* __restrict__ ow, const float* __restrict__ ob,
                                              float* __restrict__ out){
  __shared__ float us[16][HID+1];
  __shared__ float vs[64][HID+1];
  __shared__ float wo[HID];
  int tid = threadIdx.x;
  int jb = blockIdx.x*64, ib = blockIdx.y*16;
  for(int t=tid; t<16*HID; t+=256) us[t>>5][t&31] = u[(size_t)(ib + (t>>5))*HID + (t&31)];
  for(int t=tid; t<64*HID; t+=256) vs[t>>5][t&31] = v[(size_t)(jb + (t>>5))*HID + (t&31)];
  if(tid<HID) wo[tid]=ow[tid];
  __syncthreads();
  int tx = tid&63, ty = tid>>6;
  float a0=0.f, a1=0.f, a2=0.f, a3=0.f;
  #pragma unroll
  for(int c=0;c<HID;c++){
    float vv = vs[tx][c];
    float w  = wo[c];
    a0 += fmaxf(us[ty   ][c]+vv, 0.f)*w;
    a1 += fmaxf(us[ty+4 ][c]+vv, 0.f)*w;
    a2 += fmaxf(us[ty+8 ][c]+vv, 0.f)*w;
    a3 += fmaxf(us[ty+12][c]+vv, 0.f)*w;
  }
  float o0 = ob[0];
  size_t base = (size_t)ib*2048 + jb + tx;
  out[base + (size_t)(ty   )*2048] = a0+o0;
  out[base + (size_t)(ty+4 )*2048] = a1+o0;
  out[base + (size_t)(ty+8 )*2048] = a2+o0;
  out[base + (size_t)(ty+12)*2048] = a3+o0;
}

extern "C" void kernel_launch(void* const* d_in, const int* in_sizes, int n_in,
                              void* d_out, int out_size, void* d_ws, size_t ws_size,
                              hipStream_t stream){
  const int*   x     = (const int*)d_in[0];
  const int*   ei    = (const int*)d_in[1];
  const int*   entry = (const int*)d_in[2];
  const float* emb   = (const float*)d_in[3];
  const float* gamma = (const float*)d_in[4];
  const float* beta  = (const float*)d_in[5];
  const float* convw = (const float*)d_in[6];
  const float* convb = (const float*)d_in[7];
  const float* hw    = (const float*)d_in[8];
  const float* hb    = (const float*)d_in[9];
  const float* ow    = (const float*)d_in[10];
  const float* ob    = (const float*)d_in[11];
  const int* srcp = ei;
  const int* dstp = ei + NEDGES;

  // workspace (~72 MB)
  char* ws = (char*)d_ws;
  size_t o = 0;
  auto alloc = [&](size_t bytes){ void* p = ws + o; o += (bytes + 255) & ~(size_t)255; return p; };
  int*      cnt    = (int*)     alloc((size_t)NCHUNK*NBUCK*4);   // 6.4 MB
  int*      total  = (int*)     alloc(NBUCK*4);
  int*      bbase  = (int*)     alloc((NBUCK+1)*4);
  unsigned* binned = (unsigned*)alloc((size_t)NEDGES*4);         // 25.6 MB (dst-bucket runs)
  unsigned* binned2= (unsigned*)alloc((size_t)NEDGES*4);         // 25.6 MB (src-sorted runs)
  float*    dinv   = (float*)   alloc(NNODES*4);
  float*    h      = (float*)   alloc((size_t)NNODES*CH*4);
  __half*   hts16  = (__half*)  alloc((size_t)NNODES*CH*2);      // 3.2 MB
  float*    stats  = (float*)   alloc((size_t)(NCONV+1)*SSLOT*4);// 147 KB (multi-copy, line-padded)
  float*    ub     = (float*)   alloc((size_t)NENT*HID*4);
  float*    vb     = (float*)   alloc((size_t)NENT*HID*4);
  (void)ws_size; (void)in_sizes; (void)n_in; (void)out_size;

  // ---- deterministic CSR build + src-bin re-sort ----
  k_chist<<<NCHUNK, 256, 0, stream>>>(dstp, cnt, NEDGES);
  k_cscan<<<NBUCK, 256, 0, stream>>>(cnt, total);
  k_bscan<<<1, 1024, 0, stream>>>(total, bbase);
  k_bin  <<<NCHUNK, 1024, 0, stream>>>(srcp, dstp, cnt, bbase, binned, NEDGES);
  k_sub  <<<NBUCK, 512, 0, stream>>>(binned, bbase, binned2, dinv, NNODES);

  hipMemsetAsync(stats, 0, (size_t)(NCONV+1)*SSLOT*sizeof(float), stream);
  k_init_h<<<(NNODES+255)/256, 256, 0, stream>>>(x, emb, h, stats, NNODES);

  for(int l=0; l<NCONV; l++){
    k_ht  <<<(NNODES+255)/256, 256, 0, stream>>>(h, stats + (size_t)l*SSLOT, gamma, beta, convw,
                                                 dinv, hts16, l, NNODES);
    k_push<<<NBUCK, 512, 0, stream>>>(binned2, bbase, hts16, dinv, convb, h,
                                      stats + (size_t)(l+1)*SSLOT, l, NNODES);
  }

  k_uv<<<NENT/256, 256, 0, stream>>>(entry, h, hw, hb, ub, vb);
  dim3 pg(2048/64, 2048/16);
  k_pair<<<pg, 256, 0, stream>>>(ub, vb, ow, ob, (float*)d_out);
}

// Round 20
// 487.784 us; speedup vs baseline: 3.4842x; 1.0154x over previous
//
#include <hip/hip_runtime.h>
#include <hip/hip_fp16.h>

#define NNODES 200000
#define NEDGES 6400000
#define NENT   2048
#define CH     8
#define HID    32
#define NCONV  8
#define BN_EPS 1e-5f

#define BSZ    196                                  // nodes per dst-bucket
#define NBUCK  1024                                 // 1024 buckets -> exactly 4 blocks/CU
#define SRCB   391                                  // src bins (src>>9)
#define CHUNK  4096
#define NCHUNK ((NEDGES + CHUNK - 1) / CHUNK)       // 1563
#define SPAD   16                                   // one 64B line per stat-copy
#define SCOP   16                                   // stat copies (bounds same-line atomic serialization)
#define SUBCAP 8192                                 // staged edges per bucket (32 KB; run ~6272)
#define ESTG   512                                  // k_push edge stage size

#define FXSCALE   2097152.0f                        // 2^21 fixed-point scale for LDS int accumulation
#define FXINV     (1.0f/2097152.0f)

// stats slot layout: [stat t (0..15)][copy c (0..15)] each on its own 64B line
#define SSLOT  (2*CH*SCOP*SPAD)                     // floats per layer slot (4096)

__device__ __forceinline__ int bucket_of(int d){ return (int)((unsigned)d / 196u); }

// ---------------- phase A: per-chunk bucket histogram ----------------
__global__ __launch_bounds__(256) void k_chist(const int* __restrict__ dst, int* __restrict__ cnt, int E){
  __shared__ int hist[NBUCK];
  for(int t=threadIdx.x; t<NBUCK; t+=256) hist[t]=0;
  __syncthreads();
  int e0 = blockIdx.x*CHUNK;
  int n = min(CHUNK, E-e0);
  for(int i=threadIdx.x; i<n; i+=256) atomicAdd(&hist[bucket_of(dst[e0+i])], 1);
  __syncthreads();
  for(int t=threadIdx.x; t<NBUCK; t+=256) cnt[(size_t)blockIdx.x*NBUCK + t] = hist[t];
}

// ---------------- phase B1: per-bucket exclusive scan over chunks ----------------
__global__ __launch_bounds__(256) void k_cscan(int* __restrict__ cnt, int* __restrict__ total){
  int b = blockIdx.x;
  __shared__ int sd[256];
  int carry = 0;
  for(int base=0; base<NCHUNK; base+=256){
    int c = base + threadIdx.x;
    int v = (c<NCHUNK) ? cnt[(size_t)c*NBUCK + b] : 0;
    sd[threadIdx.x] = v; __syncthreads();
    #pragma unroll
    for(int o=1; o<256; o<<=1){
      int x = (threadIdx.x>=o) ? sd[threadIdx.x-o] : 0;
      __syncthreads();
      sd[threadIdx.x] += x;
      __syncthreads();
    }
    if(c<NCHUNK) cnt[(size_t)c*NBUCK + b] = carry + sd[threadIdx.x] - v;  // exclusive
    carry += sd[255];
    __syncthreads();
  }
  if(threadIdx.x==0) total[b] = carry;
}

// ---------------- phase B2: bucket base scan (1024 bins, 1024 threads) ----------------
__global__ __launch_bounds__(1024) void k_bscan(const int* __restrict__ total, int* __restrict__ bbase){
  __shared__ int sd[1024];
  int t = threadIdx.x;
  int v = total[t];
  sd[t] = v; __syncthreads();
  #pragma unroll
  for(int o=1; o<1024; o<<=1){
    int x = (t>=o) ? sd[t-o] : 0;
    __syncthreads();
    sd[t] += x;
    __syncthreads();
  }
  bbase[t] = sd[t] - v;
  if(t==1023) bbase[NBUCK] = sd[1023];   // == NEDGES
}

// ---------------- phase C: LDS counting-sort scatter into bucket runs ----------------
// packed edge = (dst_local<<18) | src   (src<2^18, dst_local<196)
__global__ __launch_bounds__(1024) void k_bin(const int* __restrict__ src, const int* __restrict__ dst,
                                              const int* __restrict__ cnt, const int* __restrict__ bbase,
                                              unsigned int* __restrict__ binned, int E){
  __shared__ int hist[NBUCK], excl[NBUCK], cur[NBUCK], base[NBUCK];
  __shared__ unsigned int pin[CHUNK];
  __shared__ unsigned short bk_in[CHUNK];
  __shared__ unsigned int sorted[CHUNK];
  __shared__ unsigned short sbkt[CHUNK];
  __shared__ int sd[1024];
  int c = blockIdx.x;
  int e0 = c*CHUNK, n = min(CHUNK, E-e0);
  int t = threadIdx.x;
  hist[t]=0;
  __syncthreads();
  for(int i=t; i<n; i+=1024){
    int s = src[e0+i], d = dst[e0+i];
    int b = bucket_of(d);
    pin[i]   = ((unsigned)(d - b*BSZ)<<18) | (unsigned)s;
    bk_in[i] = (unsigned short)b;
    atomicAdd(&hist[b], 1);
  }
  __syncthreads();
  int hv = hist[t];
  sd[t] = hv; __syncthreads();
  #pragma unroll
  for(int o=1; o<1024; o<<=1){
    int x = (t>=o) ? sd[t-o] : 0;
    __syncthreads();
    sd[t] += x;
    __syncthreads();
  }
  {
    int ex = sd[t] - hv;
    excl[t] = ex; cur[t] = ex;
    base[t] = bbase[t] + cnt[(size_t)c*NBUCK + t];
  }
  __syncthreads();
  for(int i=t; i<n; i+=1024){
    int b = bk_in[i];
    int slot = atomicAdd(&cur[b], 1);
    sorted[slot] = pin[i];
    sbkt[slot]   = (unsigned short)b;
  }
  __syncthreads();
  for(int i=t; i<n; i+=1024){
    int b = sbkt[i];
    binned[ base[b] + (i - excl[b]) ] = sorted[i];   // contiguous runs per bucket
  }
}

// ---------------- phase D: per-bucket SRC-BIN sort, LDS-staged coalesced output ----------------
__global__ __launch_bounds__(512) void k_sub(const unsigned int* __restrict__ binned,
                                             const int* __restrict__ bbase,
                                             unsigned int* __restrict__ binned2,
                                             float* __restrict__ dinv, int N){
  __shared__ int hd[BSZ];        // dst_local degree histogram
  __shared__ int hs[SRCB];       // src-bin histogram
  __shared__ int cur[SRCB];
  __shared__ int sd[512];
  __shared__ unsigned int stage[SUBCAP];   // 32 KB
  int b = blockIdx.x;
  int t = threadIdx.x;
  if(t < BSZ)  hd[t] = 0;
  if(t < SRCB) hs[t] = 0;
  __syncthreads();
  int s0 = bbase[b], s1 = bbase[b+1];
  for(int i=s0+t; i<s1; i+=512){
    unsigned p = binned[i];
    atomicAdd(&hd[p>>18], 1);
    atomicAdd(&hs[(p & 0x3FFFF)>>9], 1);
  }
  __syncthreads();
  if(t < BSZ){
    int node = b*BSZ + t;
    if(node < N) dinv[node] = 1.0f / sqrtf((float)hd[t] + 1.0f);
  }
  int hv = (t<SRCB) ? hs[t] : 0;
  sd[t] = hv; __syncthreads();
  #pragma unroll
  for(int o=1; o<512; o<<=1){
    int x = (t>=o) ? sd[t-o] : 0;
    __syncthreads();
    sd[t] += x;
    __syncthreads();
  }
  if(t<SRCB) cur[t] = sd[t] - hv;          // stage-relative
  __syncthreads();
  int len = s1 - s0;
  if(len <= SUBCAP){
    for(int i=s0+t; i<s1; i+=512){
      unsigned p = binned[i];
      int slot = atomicAdd(&cur[(p & 0x3FFFF)>>9], 1);
      stage[slot] = p;
    }
    __syncthreads();
    for(int i=t; i<len; i+=512) binned2[s0 + i] = stage[i];   // coalesced
  } else {                                 // degenerate fallback: direct scatter
    for(int i=s0+t; i<s1; i+=512){
      unsigned p = binned[i];
      int slot = atomicAdd(&cur[(p & 0x3FFFF)>>9], 1);
      binned2[s0 + slot] = p;
    }
  }
}

// ---------------- h init: embedding gather + stats[0] (multi-copy fp32 atomics) ----------------
__global__ __launch_bounds__(256) void k_init_h(const int* __restrict__ x, const float* __restrict__ emb,
                                                float* __restrict__ h, float* __restrict__ stats0, int N){
  int i = blockIdx.x*256 + threadIdx.x;
  float v[CH];
  #pragma unroll
  for(int c=0;c<CH;c++) v[c]=0.f;
  if(i < N){
    int tt = x[i];
    const float4* ep = (const float4*)(emb + (size_t)tt*CH);
    float4 a = ep[0], b = ep[1];
    float4* hp = (float4*)(h + (size_t)i*CH);
    hp[0] = a; hp[1] = b;
    v[0]=a.x; v[1]=a.y; v[2]=a.z; v[3]=a.w; v[4]=b.x; v[5]=b.y; v[6]=b.z; v[7]=b.w;
  }
  float s[CH], q[CH];
  #pragma unroll
  for(int c=0;c<CH;c++){ s[c]=v[c]; q[c]=v[c]*v[c]; }
  #pragma unroll
  for(int off=32; off>0; off>>=1){
    #pragma unroll
    for(int c=0;c<CH;c++){ s[c]+=__shfl_down(s[c],off); q[c]+=__shfl_down(q[c],off); }
  }
  __shared__ float ls[4][2*CH];
  int wave = threadIdx.x>>6, lane = threadIdx.x&63;
  if(lane==0){
    #pragma unroll
    for(int c=0;c<CH;c++){ ls[wave][c]=s[c]; ls[wave][CH+c]=q[c]; }
  }
  __syncthreads();
  if(threadIdx.x < 2*CH){
    float tsum = ls[0][threadIdx.x]+ls[1][threadIdx.x]+ls[2][threadIdx.x]+ls[3][threadIdx.x];
    unsafeAtomicAdd(&stats0[(threadIdx.x*SCOP + (blockIdx.x & (SCOP-1)))*SPAD], tsum);
  }
}

// ---------------- per-node transform: reduce stat copies, fold BN, hts16 = fp16((h@A+c0)*dinv) ----------------
__global__ __launch_bounds__(256) void k_ht(const float* __restrict__ h, const float* __restrict__ stats_l,
                                            const float* __restrict__ gamma, const float* __restrict__ beta,
                                            const float* __restrict__ convw,
                                            const float* __restrict__ dinv,
                                            __half* __restrict__ hts16, int l, int N){
  __shared__ float A[CH*CH], c0[CH], sA[CH], sT[CH];
  int t = threadIdx.x;
  if(t < CH){
    float mu = 0.f, ex2 = 0.f;
    #pragma unroll
    for(int c=0;c<SCOP;c++){
      mu  += stats_l[((t   )*SCOP + c)*SPAD];
      ex2 += stats_l[((CH+t)*SCOP + c)*SPAD];
    }
    const float invN = 1.0f / (float)NNODES;
    mu *= invN; ex2 *= invN;
    float var = ex2 - mu*mu;
    float r   = 1.0f / sqrtf(var + BN_EPS);
    float sc  = r * gamma[l*CH+t];
    sA[t] = sc;
    sT[t] = beta[l*CH+t] - mu*sc;
  }
  __syncthreads();
  if(t < CH*CH){
    int ci = t>>3, co = t&7;
    A[t] = sA[ci] * convw[(l*CH+ci)*CH+co];
  }
  if(t < CH){
    float a = 0.f;
    #pragma unroll
    for(int ci=0;ci<CH;ci++) a += sT[ci]*convw[(l*CH+ci)*CH+t];
    c0[t] = a;
  }
  __syncthreads();
  int i = blockIdx.x*blockDim.x + threadIdx.x;
  if(i >= N) return;
  const float4* hp = (const float4*)(h + (size_t)i*CH);
  float4 a = hp[0], b = hp[1];
  float v[CH] = {a.x,a.y,a.z,a.w,b.x,b.y,b.z,b.w};
  float o[CH];
  #pragma unroll
  for(int co=0;co<CH;co++) o[co]=c0[co];
  #pragma unroll
  for(int ci=0;ci<CH;ci++){
    float vv = v[ci];
    #pragma unroll
    for(int co=0;co<CH;co++) o[co] += vv*A[ci*CH+co];
  }
  float dn = dinv[i];
  union { __half hh[CH]; uint4 u; } pk;
  #pragma unroll
  for(int c=0;c<CH;c++) pk.hh[c] = __float2half(o[c]*dn);
  *(uint4*)(hts16 + (size_t)i*CH) = pk.u;
}

// ---------------- src-sorted bucket push + FUSED finalize (LDS edge-staging) ----------------
// 1024 blocks (4/CU balanced), 512 threads, 8 lanes/edge.
// binned2 staged through LDS in 512-edge sweeps: coalesced global load + broadcast
// ds_read replaces 4 redundant VMEM loads per batch (halves VMEM instruction count).
__global__ __launch_bounds__(512) void k_push(const unsigned int* __restrict__ binned2,
                                              const int* __restrict__ bbase,
                                              const __half* __restrict__ hts16,
                                              const float* __restrict__ dinv,
                                              const float* __restrict__ convb,
                                              float* __restrict__ h, float* __restrict__ stats_next,
                                              int l, int N){
  __shared__ int acc[BSZ*CH];        // 6.1 KB, fixed-point 2^21
  __shared__ unsigned est[ESTG];     // 2 KB edge stage
  int b = blockIdx.x, t = threadIdx.x;
  for(int i=t; i<BSZ*CH; i+=512) acc[i] = 0;
  __syncthreads();
  int s0 = bbase[b], s1 = bbase[b+1];
  int lane8 = t & 7;
  int g = t >> 3;                          // 0..63
  for(int off = s0; off < s1; off += ESTG){
    int n = min(ESTG, s1 - off);
    if(t < n) est[t] = binned2[off + t];   // coalesced
    __syncthreads();
    for(int e = g*4; e < n; e += 256){
      int m = n - e;
      if(m >= 4){
        unsigned p0 = est[e], p1 = est[e+1], p2 = est[e+2], p3 = est[e+3];  // ds_read broadcast
        float v0 = __half2float(hts16[(size_t)(p0 & 0x3FFFF)*CH + lane8]);
        float v1 = __half2float(hts16[(size_t)(p1 & 0x3FFFF)*CH + lane8]);
        float v2 = __half2float(hts16[(size_t)(p2 & 0x3FFFF)*CH + lane8]);
        float v3 = __half2float(hts16[(size_t)(p3 & 0x3FFFF)*CH + lane8]);
        atomicAdd(&acc[(p0>>18)*CH + lane8], __float2int_rn(v0*FXSCALE));
        atomicAdd(&acc[(p1>>18)*CH + lane8], __float2int_rn(v1*FXSCALE));
        atomicAdd(&acc[(p2>>18)*CH + lane8], __float2int_rn(v2*FXSCALE));
        atomicAdd(&acc[(p3>>18)*CH + lane8], __float2int_rn(v3*FXSCALE));
      } else {
        for(int i=0; i<m; i++){
          unsigned p = est[e+i];
          float v = __half2float(hts16[(size_t)(p & 0x3FFFF)*CH + lane8]);
          atomicAdd(&acc[(p>>18)*CH + lane8], __float2int_rn(v*FXSCALE));
        }
      }
    }
    __syncthreads();
  }
  // epilogue: thread t<BSZ owns node b*BSZ+t (this block exclusively owns these dsts)
  float vv[CH];
  #pragma unroll
  for(int c=0;c<CH;c++) vv[c]=0.f;
  int node = b*BSZ + t;
  if(t < BSZ && node < N){
    const int4* ar = (const int4*)(acc + t*CH);
    int4 a0 = ar[0], a1 = ar[1];
    float av[CH] = {(float)a0.x*FXINV,(float)a0.y*FXINV,(float)a0.z*FXINV,(float)a0.w*FXINV,
                    (float)a1.x*FXINV,(float)a1.y*FXINV,(float)a1.z*FXINV,(float)a1.w*FXINV};
    uint4 su = *(const uint4*)(hts16 + (size_t)node*CH);    // self loop (pre-scaled)
    const __half2* sp = (const __half2*)&su;
    float sv[CH];
    #pragma unroll
    for(int j=0;j<4;j++){
      float2 f = __half22float2(sp[j]);
      sv[2*j] = f.x; sv[2*j+1] = f.y;
    }
    const float4* hp = (const float4*)(h + (size_t)node*CH);
    float4 h0 = hp[0], h1 = hp[1];
    float hv2[CH] = {h0.x,h0.y,h0.z,h0.w,h1.x,h1.y,h1.z,h1.w};
    float dn = dinv[node];
    #pragma unroll
    for(int c=0;c<CH;c++){
      float r = hv2[c] + convb[l*CH + c] + dn*(av[c] + sv[c]);
      vv[c] = fmaxf(r, 0.f);
    }
    float4* hw4 = (float4*)(h + (size_t)node*CH);
    hw4[0] = make_float4(vv[0],vv[1],vv[2],vv[3]);
    hw4[1] = make_float4(vv[4],vv[5],vv[6],vv[7]);
  }
  // next-layer BN stats (multi-copy atomics: copy = b & 15)
  float s[CH], q[CH];
  #pragma unroll
  for(int c=0;c<CH;c++){ s[c]=vv[c]; q[c]=vv[c]*vv[c]; }
  #pragma unroll
  for(int off=32; off>0; off>>=1){
    #pragma unroll
    for(int c=0;c<CH;c++){ s[c]+=__shfl_down(s[c],off); q[c]+=__shfl_down(q[c],off); }
  }
  __shared__ float ls[8][2*CH];
  int wave = t>>6, lane = t&63;
  if(lane==0){
    #pragma unroll
    for(int c=0;c<CH;c++){ ls[wave][c]=s[c]; ls[wave][CH+c]=q[c]; }
  }
  __syncthreads();
  if(t < 2*CH){
    float tot = 0.f;
    #pragma unroll
    for(int w=0; w<8; w++) tot += ls[w][t];
    unsafeAtomicAdd(&stats_next[(t*SCOP + (b & (SCOP-1)))*SPAD], tot);
  }
}

// ---------------- entries: u = xe@W1, v = xe@W2 + hb ----------------
__global__ __launch_bounds__(256) void k_uv(const int* __restrict__ entry, const float* __restrict__ h,
                                            const float* __restrict__ hw, const float* __restrict__ hb,
                                            float* __restrict__ u, float* __restrict__ v){
  __shared__ float w[2*CH*HID];
  __shared__ float b[HID];
  for(int t=threadIdx.x; t<2*CH*HID; t+=256) w[t]=hw[t];
  if(threadIdx.x<HID) b[threadIdx.x]=hb[threadIdx.x];
  __syncthreads();
  int k = blockIdx.x*blockDim.x + threadIdx.x;
  if(k >= NENT) return;
  int node = entry[k];
  const float4* hp = (const float4*)(h + (size_t)node*CH);
  float4 a = hp[0], b4 = hp[1];
  float xe[CH] = {a.x,a.y,a.z,a.w,b4.x,b4.y,b4.z,b4.w};
  #pragma unroll 4
  for(int c=0;c<HID;c++){
    float uu = 0.f, vv = b[c];
    #pragma unroll
    for(int ci=0;ci<CH;ci++){
      uu += xe[ci]*w[ci*HID+c];
      vv += xe[ci]*w[(CH+ci)*HID+c];
    }
    u[(size_t)k*HID+c] = uu;
    v[(size_t)k*HID+c] = vv;
  }
}

// ---------------- pairwise scorer ----------------
__global__ __launch_bounds__(256) void k_pair(const float* __restrict__ u, const float* __restrict__ v,
                                              const float* __restrict__ ow, const float* __restrict__ ob,
                                              float* __restrict__ out){
  __shared__ float us[16][HID+1];
  __shared__ float vs[64][HID+1];
  __shared__ float wo[HID];
  int tid = threadIdx.x;
  int jb = blockIdx.x*64, ib = blockIdx.y*16;
  for(int t=tid; t<16*HID; t+=256) us[t>>5][t&31] = u[(size_t)(ib + (t>>5))*HID + (t&31)];
  for(int t=tid; t<64*HID; t+=256) vs[t>>5][t&31] = v[(size_t)(jb + (t>>5))*HID + (t&31)];
  if(tid<HID) wo[tid]=ow[tid];
  __syncthreads();
  int tx = tid&63, ty = tid>>6;
  float a0=0.f, a1=0.f, a2=0.f, a3=0.f;
  #pragma unroll
  for(int c=0;c<HID;c++){
    float vv = vs[tx][c];
    float w  = wo[c];
    a0 += fmaxf(us[ty   ][c]+vv, 0.f)*w;
    a1 += fmaxf(us[ty+4 ][c]+vv, 0.f)*w;
    a2 += fmaxf(us[ty+8 ][c]+vv, 0.f)*w;
    a3 += fmaxf(us[ty+12][c]+vv, 0.f)*w;
  }
  float o0 = ob[0];
  size_t base = (size_t)ib*2048 + jb + tx;
  out[base + (size_t)(ty   )*2048] = a0+o0;
  out[base + (size_t)(ty+4 )*2048] = a1+o0;
  out[base + (size_t)(ty+8 )*2048] = a2+o0;
  out[base + (size_t)(ty+12)*2048] = a3+o0;
}

extern "C" void kernel_launch(void* const* d_in, const int* in_sizes, int n_in,
                              void* d_out, int out_size, void* d_ws, size_t ws_size,
                              hipStream_t stream){
  const int*   x     = (const int*)d_in[0];
  const int*   ei    = (const int*)d_in[1];
  const int*   entry = (const int*)d_in[2];
  const float* emb   = (const float*)d_in[3];
  const float* gamma = (const float*)d_in[4];
  const float* beta  = (const float*)d_in[5];
  const float* convw = (const float*)d_in[6];
  const float* convb = (const float*)d_in[7];
  const float* hw    = (const float*)d_in[8];
  const float* hb    = (const float*)d_in[9];
  const float* ow    = (const float*)d_in[10];
  const float* ob    = (const float*)d_in[11];
  const int* srcp = ei;
  const int* dstp = ei + NEDGES;

  // workspace (~72 MB)
  char* ws = (char*)d_ws;
  size_t o = 0;
  auto alloc = [&](size_t bytes){ void* p = ws + o; o += (bytes + 255) & ~(size_t)255; return p; };
  int*      cnt    = (int*)     alloc((size_t)NCHUNK*NBUCK*4);   // 6.4 MB
  int*      total  = (int*)     alloc(NBUCK*4);
  int*      bbase  = (int*)     alloc((NBUCK+1)*4);
  unsigned* binned = (unsigned*)alloc((size_t)NEDGES*4);         // 25.6 MB (dst-bucket runs)
  unsigned* binned2= (unsigned*)alloc((size_t)NEDGES*4);         // 25.6 MB (src-sorted runs)
  float*    dinv   = (float*)   alloc(NNODES*4);
  float*    h      = (float*)   alloc((size_t)NNODES*CH*4);
  __half*   hts16  = (__half*)  alloc((size_t)NNODES*CH*2);      // 3.2 MB
  float*    stats  = (float*)   alloc((size_t)(NCONV+1)*SSLOT*4);// 147 KB (multi-copy, line-padded)
  float*    ub     = (float*)   alloc((size_t)NENT*HID*4);
  float*    vb     = (float*)   alloc((size_t)NENT*HID*4);
  (void)ws_size; (void)in_sizes; (void)n_in; (void)out_size;

  // ---- deterministic CSR build + src-bin re-sort ----
  k_chist<<<NCHUNK, 256, 0, stream>>>(dstp, cnt, NEDGES);
  k_cscan<<<NBUCK, 256, 0, stream>>>(cnt, total);
  k_bscan<<<1, 1024, 0, stream>>>(total, bbase);
  k_bin  <<<NCHUNK, 1024, 0, stream>>>(srcp, dstp, cnt, bbase, binned, NEDGES);
  k_sub  <<<NBUCK, 512, 0, stream>>>(binned, bbase, binned2, dinv, NNODES);

  hipMemsetAsync(stats, 0, (size_t)(NCONV+1)*SSLOT*sizeof(float), stream);
  k_init_h<<<(NNODES+255)/256, 256, 0, stream>>>(x, emb, h, stats, NNODES);

  for(int l=0; l<NCONV; l++){
    k_ht  <<<(NNODES+255)/256, 256, 0, stream>>>(h, stats + (size_t)l*SSLOT, gamma, beta, convw,
                                                 dinv, hts16, l, NNODES);
    k_push<<<NBUCK, 512, 0, stream>>>(binned2, bbase, hts16, dinv, convb, h,
                                      stats + (size_t)(l+1)*SSLOT, l, NNODES);
  }

  k_uv<<<NENT/256, 256, 0, stream>>>(entry, h, hw, hb, ub, vb);
  dim3 pg(2048/64, 2048/16);
  k_pair<<<pg, 256, 0, stream>>>(ub, vb, ow, ob, (float*)d_out);
}

// Round 21
// 471.062 us; speedup vs baseline: 3.6078x; 1.0355x over previous
//
#include <hip/hip_runtime.h>
#include <hip/hip_fp16.h>

#define NNODES 200000
#define NEDGES 6400000
#define NENT   2048
#define CH     8
#define HID    32
#define NCONV  8
#define BN_EPS 1e-5f

#define BSZ    196                                  // nodes per dst-bucket
#define NBUCK  1024                                 // 1024 buckets -> exactly 4 blocks/CU
#define SRCB   391                                  // src bins (src>>9)
#define CHUNK  4096
#define NCHUNK ((NEDGES + CHUNK - 1) / CHUNK)       // 1563
#define SPAD   16                                   // one 64B line per stat-copy
#define SCOP   16                                   // stat copies (bounds same-line atomic serialization)
#define SUBCAP 8192                                 // staged edges per bucket (32 KB; run ~6272)
#define ESTG   512                                  // k_push edge stage size

#define FXSCALE   2097152.0f                        // 2^21 fixed-point scale for LDS int accumulation
#define FXINV     (1.0f/2097152.0f)

// stats slot layout: [stat t (0..15)][copy c (0..15)] each on its own 64B line
#define SSLOT  (2*CH*SCOP*SPAD)                     // floats per layer slot (4096)

__device__ __forceinline__ int bucket_of(int d){ return (int)((unsigned)d / 196u); }

// bijective XCD-chunked swizzle (m204 form): consecutive work-ids land on one XCD
__device__ __forceinline__ int xcd_swz(int bid, int nwg){
  int xcd = bid & 7, idx = bid >> 3;
  int q = nwg >> 3, r = nwg & 7;
  return (xcd < r ? xcd*(q+1) : r*(q+1) + (xcd-r)*q) + idx;
}

// ---------------- phase A: per-chunk bucket histogram ----------------
__global__ __launch_bounds__(256) void k_chist(const int* __restrict__ dst, int* __restrict__ cnt, int E){
  __shared__ int hist[NBUCK];
  for(int t=threadIdx.x; t<NBUCK; t+=256) hist[t]=0;
  __syncthreads();
  int e0 = blockIdx.x*CHUNK;
  int n = min(CHUNK, E-e0);
  for(int i=threadIdx.x; i<n; i+=256) atomicAdd(&hist[bucket_of(dst[e0+i])], 1);
  __syncthreads();
  for(int t=threadIdx.x; t<NBUCK; t+=256) cnt[(size_t)blockIdx.x*NBUCK + t] = hist[t];
}

// ---------------- phase B1: per-bucket exclusive scan over chunks (XCD-swizzled) ----------------
__global__ __launch_bounds__(256) void k_cscan(int* __restrict__ cnt, int* __restrict__ total){
  int b = xcd_swz(blockIdx.x, NBUCK);     // adjacent buckets on same XCD -> shared lines merge
  __shared__ int sd[256];
  int carry = 0;
  for(int base=0; base<NCHUNK; base+=256){
    int c = base + threadIdx.x;
    int v = (c<NCHUNK) ? cnt[(size_t)c*NBUCK + b] : 0;
    sd[threadIdx.x] = v; __syncthreads();
    #pragma unroll
    for(int o=1; o<256; o<<=1){
      int x = (threadIdx.x>=o) ? sd[threadIdx.x-o] : 0;
      __syncthreads();
      sd[threadIdx.x] += x;
      __syncthreads();
    }
    if(c<NCHUNK) cnt[(size_t)c*NBUCK + b] = carry + sd[threadIdx.x] - v;  // exclusive
    carry += sd[255];
    __syncthreads();
  }
  if(threadIdx.x==0) total[b] = carry;
}

// ---------------- phase B2: bucket base scan (1024 bins, 1024 threads) ----------------
__global__ __launch_bounds__(1024) void k_bscan(const int* __restrict__ total, int* __restrict__ bbase){
  __shared__ int sd[1024];
  int t = threadIdx.x;
  int v = total[t];
  sd[t] = v; __syncthreads();
  #pragma unroll
  for(int o=1; o<1024; o<<=1){
    int x = (t>=o) ? sd[t-o] : 0;
    __syncthreads();
    sd[t] += x;
    __syncthreads();
  }
  bbase[t] = sd[t] - v;
  if(t==1023) bbase[NBUCK] = sd[1023];   // == NEDGES
}

// ---------------- phase C: LDS counting-sort scatter into bucket runs ----------------
// packed edge = (dst_local<<18) | src   (src<2^18, dst_local<196)
// XCD-swizzled chunks: adjacent chunks share an XCD so partial-line writes at run
// boundaries merge in that XCD's L2 (69 MB -> ~payload). Histogram derived from
// cscan's adjacent prefixes (no atomic pass).
__global__ __launch_bounds__(1024) void k_bin(const int* __restrict__ src, const int* __restrict__ dst,
                                              const int* __restrict__ cnt, const int* __restrict__ total,
                                              const int* __restrict__ bbase,
                                              unsigned int* __restrict__ binned, int E){
  __shared__ int excl[NBUCK], cur[NBUCK], base[NBUCK];
  __shared__ unsigned int pin[CHUNK];
  __shared__ unsigned short bk_in[CHUNK];
  __shared__ unsigned int sorted[CHUNK];
  __shared__ unsigned short sbkt[CHUNK];
  __shared__ int sd[1024];
  int c = xcd_swz(blockIdx.x, NCHUNK);
  int e0 = c*CHUNK, n = min(CHUNK, E-e0);
  int t = threadIdx.x;
  for(int i=t; i<n; i+=1024){
    int s = src[e0+i], d = dst[e0+i];
    int b = bucket_of(d);
    pin[i]   = ((unsigned)(d - b*BSZ)<<18) | (unsigned)s;
    bk_in[i] = (unsigned short)b;
  }
  int h0 = cnt[(size_t)c*NBUCK + t];
  int h1 = (c+1 < NCHUNK) ? cnt[(size_t)(c+1)*NBUCK + t] : total[t];
  int hv = h1 - h0;                        // this chunk's count for bucket t
  sd[t] = hv; __syncthreads();
  #pragma unroll
  for(int o=1; o<1024; o<<=1){
    int x = (t>=o) ? sd[t-o] : 0;
    __syncthreads();
    sd[t] += x;
    __syncthreads();
  }
  {
    int ex = sd[t] - hv;
    excl[t] = ex; cur[t] = ex;
    base[t] = bbase[t] + h0;
  }
  __syncthreads();
  for(int i=t; i<n; i+=1024){
    int b = bk_in[i];
    int slot = atomicAdd(&cur[b], 1);
    sorted[slot] = pin[i];
    sbkt[slot]   = (unsigned short)b;
  }
  __syncthreads();
  for(int i=t; i<n; i+=1024){
    int b = sbkt[i];
    binned[ base[b] + (i - excl[b]) ] = sorted[i];   // contiguous runs per bucket
  }
}

// ---------------- phase D: per-bucket SRC-BIN sort, LDS-staged coalesced output ----------------
__global__ __launch_bounds__(512) void k_sub(const unsigned int* __restrict__ binned,
                                             const int* __restrict__ bbase,
                                             unsigned int* __restrict__ binned2,
                                             float* __restrict__ dinv, int N){
  __shared__ int hd[BSZ];        // dst_local degree histogram
  __shared__ int hs[SRCB];       // src-bin histogram
  __shared__ int cur[SRCB];
  __shared__ int sd[512];
  __shared__ unsigned int stage[SUBCAP];   // 32 KB
  int b = blockIdx.x;
  int t = threadIdx.x;
  if(t < BSZ)  hd[t] = 0;
  if(t < SRCB) hs[t] = 0;
  __syncthreads();
  int s0 = bbase[b], s1 = bbase[b+1];
  for(int i=s0+t; i<s1; i+=512){
    unsigned p = binned[i];
    atomicAdd(&hd[p>>18], 1);
    atomicAdd(&hs[(p & 0x3FFFF)>>9], 1);
  }
  __syncthreads();
  if(t < BSZ){
    int node = b*BSZ + t;
    if(node < N) dinv[node] = 1.0f / sqrtf((float)hd[t] + 1.0f);
  }
  int hv = (t<SRCB) ? hs[t] : 0;
  sd[t] = hv; __syncthreads();
  #pragma unroll
  for(int o=1; o<512; o<<=1){
    int x = (t>=o) ? sd[t-o] : 0;
    __syncthreads();
    sd[t] += x;
    __syncthreads();
  }
  if(t<SRCB) cur[t] = sd[t] - hv;          // stage-relative
  __syncthreads();
  int len = s1 - s0;
  if(len <= SUBCAP){
    for(int i=s0+t; i<s1; i+=512){
      unsigned p = binned[i];
      int slot = atomicAdd(&cur[(p & 0x3FFFF)>>9], 1);
      stage[slot] = p;
    }
    __syncthreads();
    for(int i=t; i<len; i+=512) binned2[s0 + i] = stage[i];   // coalesced
  } else {                                 // degenerate fallback: direct scatter
    for(int i=s0+t; i<s1; i+=512){
      unsigned p = binned[i];
      int slot = atomicAdd(&cur[(p & 0x3FFFF)>>9], 1);
      binned2[s0 + slot] = p;
    }
  }
}

// ---------------- h init: embedding gather + stats[0] (multi-copy fp32 atomics) ----------------
__global__ __launch_bounds__(256) void k_init_h(const int* __restrict__ x, const float* __restrict__ emb,
                                                float* __restrict__ h, float* __restrict__ stats0, int N){
  int i = blockIdx.x*256 + threadIdx.x;
  float v[CH];
  #pragma unroll
  for(int c=0;c<CH;c++) v[c]=0.f;
  if(i < N){
    int tt = x[i];
    const float4* ep = (const float4*)(emb + (size_t)tt*CH);
    float4 a = ep[0], b = ep[1];
    float4* hp = (float4*)(h + (size_t)i*CH);
    hp[0] = a; hp[1] = b;
    v[0]=a.x; v[1]=a.y; v[2]=a.z; v[3]=a.w; v[4]=b.x; v[5]=b.y; v[6]=b.z; v[7]=b.w;
  }
  float s[CH], q[CH];
  #pragma unroll
  for(int c=0;c<CH;c++){ s[c]=v[c]; q[c]=v[c]*v[c]; }
  #pragma unroll
  for(int off=32; off>0; off>>=1){
    #pragma unroll
    for(int c=0;c<CH;c++){ s[c]+=__shfl_down(s[c],off); q[c]+=__shfl_down(q[c],off); }
  }
  __shared__ float ls[4][2*CH];
  int wave = threadIdx.x>>6, lane = threadIdx.x&63;
  if(lane==0){
    #pragma unroll
    for(int c=0;c<CH;c++){ ls[wave][c]=s[c]; ls[wave][CH+c]=q[c]; }
  }
  __syncthreads();
  if(threadIdx.x < 2*CH){
    float tsum = ls[0][threadIdx.x]+ls[1][threadIdx.x]+ls[2][threadIdx.x]+ls[3][threadIdx.x];
    unsafeAtomicAdd(&stats0[(threadIdx.x*SCOP + (blockIdx.x & (SCOP-1)))*SPAD], tsum);
  }
}

// ---------------- per-node transform: reduce stat copies, fold BN, hts16 = fp16((h@A+c0)*dinv) ----------------
__global__ __launch_bounds__(256) void k_ht(const float* __restrict__ h, const float* __restrict__ stats_l,
                                            const float* __restrict__ gamma, const float* __restrict__ beta,
                                            const float* __restrict__ convw,
                                            const float* __restrict__ dinv,
                                            __half* __restrict__ hts16, int l, int N){
  __shared__ float A[CH*CH], c0[CH], sA[CH], sT[CH];
  int t = threadIdx.x;
  if(t < CH){
    float mu = 0.f, ex2 = 0.f;
    #pragma unroll
    for(int c=0;c<SCOP;c++){
      mu  += stats_l[((t   )*SCOP + c)*SPAD];
      ex2 += stats_l[((CH+t)*SCOP + c)*SPAD];
    }
    const float invN = 1.0f / (float)NNODES;
    mu *= invN; ex2 *= invN;
    float var = ex2 - mu*mu;
    float r   = 1.0f / sqrtf(var + BN_EPS);
    float sc  = r * gamma[l*CH+t];
    sA[t] = sc;
    sT[t] = beta[l*CH+t] - mu*sc;
  }
  __syncthreads();
  if(t < CH*CH){
    int ci = t>>3, co = t&7;
    A[t] = sA[ci] * convw[(l*CH+ci)*CH+co];
  }
  if(t < CH){
    float a = 0.f;
    #pragma unroll
    for(int ci=0;ci<CH;ci++) a += sT[ci]*convw[(l*CH+ci)*CH+t];
    c0[t] = a;
  }
  __syncthreads();
  int i = blockIdx.x*blockDim.x + threadIdx.x;
  if(i >= N) return;
  const float4* hp = (const float4*)(h + (size_t)i*CH);
  float4 a = hp[0], b = hp[1];
  float v[CH] = {a.x,a.y,a.z,a.w,b.x,b.y,b.z,b.w};
  float o[CH];
  #pragma unroll
  for(int co=0;co<CH;co++) o[co]=c0[co];
  #pragma unroll
  for(int ci=0;ci<CH;ci++){
    float vv = v[ci];
    #pragma unroll
    for(int co=0;co<CH;co++) o[co] += vv*A[ci*CH+co];
  }
  float dn = dinv[i];
  union { __half hh[CH]; uint4 u; } pk;
  #pragma unroll
  for(int c=0;c<CH;c++) pk.hh[c] = __float2half(o[c]*dn);
  *(uint4*)(hts16 + (size_t)i*CH) = pk.u;
}

// ---------------- src-sorted bucket push + FUSED finalize (LDS edge-staging) ----------------
__global__ __launch_bounds__(512) void k_push(const unsigned int* __restrict__ binned2,
                                              const int* __restrict__ bbase,
                                              const __half* __restrict__ hts16,
                                              const float* __restrict__ dinv,
                                              const float* __restrict__ convb,
                                              float* __restrict__ h, float* __restrict__ stats_next,
                                              int l, int N){
  __shared__ int acc[BSZ*CH];        // 6.1 KB, fixed-point 2^21
  __shared__ unsigned est[ESTG];     // 2 KB edge stage
  int b = blockIdx.x, t = threadIdx.x;
  for(int i=t; i<BSZ*CH; i+=512) acc[i] = 0;
  __syncthreads();
  int s0 = bbase[b], s1 = bbase[b+1];
  int lane8 = t & 7;
  int g = t >> 3;                          // 0..63
  for(int off = s0; off < s1; off += ESTG){
    int n = min(ESTG, s1 - off);
    if(t < n) est[t] = binned2[off + t];   // coalesced
    __syncthreads();
    for(int e = g*4; e < n; e += 256){
      int m = n - e;
      if(m >= 4){
        unsigned p0 = est[e], p1 = est[e+1], p2 = est[e+2], p3 = est[e+3];  // ds_read broadcast
        float v0 = __half2float(hts16[(size_t)(p0 & 0x3FFFF)*CH + lane8]);
        float v1 = __half2float(hts16[(size_t)(p1 & 0x3FFFF)*CH + lane8]);
        float v2 = __half2float(hts16[(size_t)(p2 & 0x3FFFF)*CH + lane8]);
        float v3 = __half2float(hts16[(size_t)(p3 & 0x3FFFF)*CH + lane8]);
        atomicAdd(&acc[(p0>>18)*CH + lane8], __float2int_rn(v0*FXSCALE));
        atomicAdd(&acc[(p1>>18)*CH + lane8], __float2int_rn(v1*FXSCALE));
        atomicAdd(&acc[(p2>>18)*CH + lane8], __float2int_rn(v2*FXSCALE));
        atomicAdd(&acc[(p3>>18)*CH + lane8], __float2int_rn(v3*FXSCALE));
      } else {
        for(int i=0; i<m; i++){
          unsigned p = est[e+i];
          float v = __half2float(hts16[(size_t)(p & 0x3FFFF)*CH + lane8]);
          atomicAdd(&acc[(p>>18)*CH + lane8], __float2int_rn(v*FXSCALE));
        }
      }
    }
    __syncthreads();
  }
  // epilogue: thread t<BSZ owns node b*BSZ+t (this block exclusively owns these dsts)
  float vv[CH];
  #pragma unroll
  for(int c=0;c<CH;c++) vv[c]=0.f;
  int node = b*BSZ + t;
  if(t < BSZ && node < N){
    const int4* ar = (const int4*)(acc + t*CH);
    int4 a0 = ar[0], a1 = ar[1];
    float av[CH] = {(float)a0.x*FXINV,(float)a0.y*FXINV,(float)a0.z*FXINV,(float)a0.w*FXINV,
                    (float)a1.x*FXINV,(float)a1.y*FXINV,(float)a1.z*FXINV,(float)a1.w*FXINV};
    uint4 su = *(const uint4*)(hts16 + (size_t)node*CH);    // self loop (pre-scaled)
    const __half2* sp = (const __half2*)&su;
    float sv[CH];
    #pragma unroll
    for(int j=0;j<4;j++){
      float2 f = __half22float2(sp[j]);
      sv[2*j] = f.x; sv[2*j+1] = f.y;
    }
    const float4* hp = (const float4*)(h + (size_t)node*CH);
    float4 h0 = hp[0], h1 = hp[1];
    float hv2[CH] = {h0.x,h0.y,h0.z,h0.w,h1.x,h1.y,h1.z,h1.w};
    float dn = dinv[node];
    #pragma unroll
    for(int c=0;c<CH;c++){
      float r = hv2[c] + convb[l*CH + c] + dn*(av[c] + sv[c]);
      vv[c] = fmaxf(r, 0.f);
    }
    float4* hw4 = (float4*)(h + (size_t)node*CH);
    hw4[0] = make_float4(vv[0],vv[1],vv[2],vv[3]);
    hw4[1] = make_float4(vv[4],vv[5],vv[6],vv[7]);
  }
  // next-layer BN stats (multi-copy atomics: copy = b & 15)
  float s[CH], q[CH];
  #pragma unroll
  for(int c=0;c<CH;c++){ s[c]=vv[c]; q[c]=vv[c]*vv[c]; }
  #pragma unroll
  for(int off=32; off>0; off>>=1){
    #pragma unroll
    for(int c=0;c<CH;c++){ s[c]+=__shfl_down(s[c],off); q[c]+=__shfl_down(q[c],off); }
  }
  __shared__ float ls[8][2*CH];
  int wave = t>>6, lane = t&63;
  if(lane==0){
    #pragma unroll
    for(int c=0;c<CH;c++){ ls[wave][c]=s[c]; ls[wave][CH+c]=q[c]; }
  }
  __syncthreads();
  if(t < 2*CH){
    float tot = 0.f;
    #pragma unroll
    for(int w=0; w<8; w++) tot += ls[w][t];
    unsafeAtomicAdd(&stats_next[(t*SCOP + (b & (SCOP-1)))*SPAD], tot);
  }
}

// ---------------- entries: u = xe@W1, v = xe@W2 + hb ----------------
__global__ __launch_bounds__(256) void k_uv(const int* __restrict__ entry, const float* __restrict__ h,
                                            const float* __restrict__ hw, const float* __restrict__ hb,
                                            float* __restrict__ u, float* __restrict__ v){
  __shared__ float w[2*CH*HID];
  __shared__ float b[HID];
  for(int t=threadIdx.x; t<2*CH*HID; t+=256) w[t]=hw[t];
  if(threadIdx.x<HID) b[threadIdx.x]=hb[threadIdx.x];
  __syncthreads();
  int k = blockIdx.x*blockDim.x + threadIdx.x;
  if(k >= NENT) return;
  int node = entry[k];
  const float4* hp = (const float4*)(h + (size_t)node*CH);
  float4 a = hp[0], b4 = hp[1];
  float xe[CH] = {a.x,a.y,a.z,a.w,b4.x,b4.y,b4.z,b4.w};
  #pragma unroll 4
  for(int c=0;c<HID;c++){
    float uu = 0.f, vv = b[c];
    #pragma unroll
    for(int ci=0;ci<CH;ci++){
      uu += xe[ci]*w[ci*HID+c];
      vv += xe[ci]*w[(CH+ci)*HID+c];
    }
    u[(size_t)k*HID+c] = uu;
    v[(size_t)k*HID+c] = vv;
  }
}

// ---------------- pairwise scorer ----------------
__global__ __launch_bounds__(256) void k_pair(const float* __restrict__ u, const float* __restrict__ v,
                                              const float* __restrict__ ow, const float* __restrict__ ob,
                                              float* __restrict__ out){
  __shared__ float us[16][HID+1];
  __shared__ float vs[64][HID+1];
  __shared__ float wo[HID];
  int tid = threadIdx.x;
  int jb = blockIdx.x*64, ib = blockIdx.y*16;
  for(int t=tid; t<16*HID; t+=256) us[t>>5][t&31] = u[(size_t)(ib + (t>>5))*HID + (t&31)];
  for(int t=tid; t<64*HID; t+=256) vs[t>>5][t&31] = v[(size_t)(jb + (t>>5))*HID + (t&31)];
  if(tid<HID) wo[tid]=ow[tid];
  __syncthreads();
  int tx = tid&63, ty = tid>>6;
  float a0=0.f, a1=0.f, a2=0.f, a3=0.f;
  #pragma unroll
  for(int c=0;c<HID;c++){
    float vv = vs[tx][c];
    float w  = wo[c];
    a0 += fmaxf(us[ty   ][c]+vv, 0.f)*w;
    a1 += fmaxf(us[ty+4 ][c]+vv, 0.f)*w;
    a2 += fmaxf(us[ty+8 ][c]+vv, 0.f)*w;
    a3 += fmaxf(us[ty+12][c]+vv, 0.f)*w;
  }
  float o0 = ob[0];
  size_t base = (size_t)ib*2048 + jb + tx;
  out[base + (size_t)(ty   )*2048] = a0+o0;
  out[base + (size_t)(ty+4 )*2048] = a1+o0;
  out[base + (size_t)(ty+8 )*2048] = a2+o0;
  out[base + (size_t)(ty+12)*2048] = a3+o0;
}

extern "C" void kernel_launch(void* const* d_in, const int* in_sizes, int n_in,
                              void* d_out, int out_size, void* d_ws, size_t ws_size,
                              hipStream_t stream){
  const int*   x     = (const int*)d_in[0];
  const int*   ei    = (const int*)d_in[1];
  const int*   entry = (const int*)d_in[2];
  const float* emb   = (const float*)d_in[3];
  const float* gamma = (const float*)d_in[4];
  const float* beta  = (const float*)d_in[5];
  const float* convw = (const float*)d_in[6];
  const float* convb = (const float*)d_in[7];
  const float* hw    = (const float*)d_in[8];
  const float* hb    = (const float*)d_in[9];
  const float* ow    = (const float*)d_in[10];
  const float* ob    = (const float*)d_in[11];
  const int* srcp = ei;
  const int* dstp = ei + NEDGES;

  // workspace (~72 MB)
  char* ws = (char*)d_ws;
  size_t o = 0;
  auto alloc = [&](size_t bytes){ void* p = ws + o; o += (bytes + 255) & ~(size_t)255; return p; };
  int*      cnt    = (int*)     alloc((size_t)NCHUNK*NBUCK*4);   // 6.4 MB
  int*      total  = (int*)     alloc(NBUCK*4);
  int*      bbase  = (int*)     alloc((NBUCK+1)*4);
  unsigned* binned = (unsigned*)alloc((size_t)NEDGES*4);         // 25.6 MB (dst-bucket runs)
  unsigned* binned2= (unsigned*)alloc((size_t)NEDGES*4);         // 25.6 MB (src-sorted runs)
  float*    dinv   = (float*)   alloc(NNODES*4);
  float*    h      = (float*)   alloc((size_t)NNODES*CH*4);
  __half*   hts16  = (__half*)  alloc((size_t)NNODES*CH*2);      // 3.2 MB
  float*    stats  = (float*)   alloc((size_t)(NCONV+1)*SSLOT*4);// 147 KB (multi-copy, line-padded)
  float*    ub     = (float*)   alloc((size_t)NENT*HID*4);
  float*    vb     = (float*)   alloc((size_t)NENT*HID*4);
  (void)ws_size; (void)in_sizes; (void)n_in; (void)out_size;

  // ---- deterministic CSR build + src-bin re-sort ----
  k_chist<<<NCHUNK, 256, 0, stream>>>(dstp, cnt, NEDGES);
  k_cscan<<<NBUCK, 256, 0, stream>>>(cnt, total);
  k_bscan<<<1, 1024, 0, stream>>>(total, bbase);
  k_bin  <<<NCHUNK, 1024, 0, stream>>>(srcp, dstp, cnt, total, bbase, binned, NEDGES);
  k_sub  <<<NBUCK, 512, 0, stream>>>(binned, bbase, binned2, dinv, NNODES);

  hipMemsetAsync(stats, 0, (size_t)(NCONV+1)*SSLOT*sizeof(float), stream);
  k_init_h<<<(NNODES+255)/256, 256, 0, stream>>>(x, emb, h, stats, NNODES);

  for(int l=0; l<NCONV; l++){
    k_ht  <<<(NNODES+255)/256, 256, 0, stream>>>(h, stats + (size_t)l*SSLOT, gamma, beta, convw,
                                                 dinv, hts16, l, NNODES);
    k_push<<<NBUCK, 512, 0, stream>>>(binned2, bbase, hts16, dinv, convb, h,
                                      stats + (size_t)(l+1)*SSLOT, l, NNODES);
  }

  k_uv<<<NENT/256, 256, 0, stream>>>(entry, h, hw, hb, ub, vb);
  dim3 pg(2048/64, 2048/16);
  k_pair<<<pg, 256, 0, stream>>>(ub, vb, ow, ob, (float*)d_out);
}

// Round 22
// 470.533 us; speedup vs baseline: 3.6119x; 1.0011x over previous
//
#include <hip/hip_runtime.h>
#include <hip/hip_fp16.h>

#define NNODES 200000
#define NEDGES 6400000
#define NENT   2048
#define CH     8
#define HID    32
#define NCONV  8
#define BN_EPS 1e-5f

#define BSZ    196                                  // nodes per dst-bucket
#define NBUCK  1024                                 // 1024 buckets -> exactly 4 blocks/CU
#define SRCB   391                                  // src bins (src>>9)
#define CHUNK  4096
#define NCHUNK ((NEDGES + CHUNK - 1) / CHUNK)       // 1563
#define SPAD   16                                   // one 64B line per stat-copy
#define SCOP   16                                   // stat copies (bounds same-line atomic serialization)
#define SUBCAP 8192                                 // staged edges per bucket (32 KB; run ~6272)
#define ESTG   512                                  // k_push edge stage size
#define ACCS   9                                    // acc stride (bank-conflict-free vs 8)

#define I16SCALE  2048.0f                           // 2^11 fixed-point scale for int16 hts
#define I16INV    (1.0f/2048.0f)

// stats slot layout: [stat t (0..15)][copy c (0..15)] each on its own 64B line
#define SSLOT  (2*CH*SCOP*SPAD)                     // floats per layer slot (4096)

__device__ __forceinline__ int bucket_of(int d){ return (int)((unsigned)d / 196u); }

// bijective XCD-chunked swizzle (m204 form): consecutive work-ids land on one XCD
__device__ __forceinline__ int xcd_swz(int bid, int nwg){
  int xcd = bid & 7, idx = bid >> 3;
  int q = nwg >> 3, r = nwg & 7;
  return (xcd < r ? xcd*(q+1) : r*(q+1) + (xcd-r)*q) + idx;
}

// ---------------- phase A: per-chunk bucket histogram ----------------
__global__ __launch_bounds__(256) void k_chist(const int* __restrict__ dst, int* __restrict__ cnt, int E){
  __shared__ int hist[NBUCK];
  for(int t=threadIdx.x; t<NBUCK; t+=256) hist[t]=0;
  __syncthreads();
  int e0 = blockIdx.x*CHUNK;
  int n = min(CHUNK, E-e0);
  for(int i=threadIdx.x; i<n; i+=256) atomicAdd(&hist[bucket_of(dst[e0+i])], 1);
  __syncthreads();
  for(int t=threadIdx.x; t<NBUCK; t+=256) cnt[(size_t)blockIdx.x*NBUCK + t] = hist[t];
}

// ---------------- phase B1: per-bucket exclusive scan over chunks (XCD-swizzled) ----------------
__global__ __launch_bounds__(256) void k_cscan(int* __restrict__ cnt, int* __restrict__ total){
  int b = xcd_swz(blockIdx.x, NBUCK);     // adjacent buckets on same XCD -> shared lines merge
  __shared__ int sd[256];
  int carry = 0;
  for(int base=0; base<NCHUNK; base+=256){
    int c = base + threadIdx.x;
    int v = (c<NCHUNK) ? cnt[(size_t)c*NBUCK + b] : 0;
    sd[threadIdx.x] = v; __syncthreads();
    #pragma unroll
    for(int o=1; o<256; o<<=1){
      int x = (threadIdx.x>=o) ? sd[threadIdx.x-o] : 0;
      __syncthreads();
      sd[threadIdx.x] += x;
      __syncthreads();
    }
    if(c<NCHUNK) cnt[(size_t)c*NBUCK + b] = carry + sd[threadIdx.x] - v;  // exclusive
    carry += sd[255];
    __syncthreads();
  }
  if(threadIdx.x==0) total[b] = carry;
}

// ---------------- phase B2: bucket base scan (1024 bins, 1024 threads) ----------------
__global__ __launch_bounds__(1024) void k_bscan(const int* __restrict__ total, int* __restrict__ bbase){
  __shared__ int sd[1024];
  int t = threadIdx.x;
  int v = total[t];
  sd[t] = v; __syncthreads();
  #pragma unroll
  for(int o=1; o<1024; o<<=1){
    int x = (t>=o) ? sd[t-o] : 0;
    __syncthreads();
    sd[t] += x;
    __syncthreads();
  }
  bbase[t] = sd[t] - v;
  if(t==1023) bbase[NBUCK] = sd[1023];   // == NEDGES
}

// ---------------- phase C: LDS counting-sort scatter into bucket runs ----------------
// packed edge = (dst_local<<18) | src   (src<2^18, dst_local<196)
__global__ __launch_bounds__(1024) void k_bin(const int* __restrict__ src, const int* __restrict__ dst,
                                              const int* __restrict__ cnt, const int* __restrict__ total,
                                              const int* __restrict__ bbase,
                                              unsigned int* __restrict__ binned, int E){
  __shared__ int excl[NBUCK], cur[NBUCK], base[NBUCK];
  __shared__ unsigned int pin[CHUNK];
  __shared__ unsigned short bk_in[CHUNK];
  __shared__ unsigned int sorted[CHUNK];
  __shared__ unsigned short sbkt[CHUNK];
  __shared__ int sd[1024];
  int c = xcd_swz(blockIdx.x, NCHUNK);
  int e0 = c*CHUNK, n = min(CHUNK, E-e0);
  int t = threadIdx.x;
  for(int i=t; i<n; i+=1024){
    int s = src[e0+i], d = dst[e0+i];
    int b = bucket_of(d);
    pin[i]   = ((unsigned)(d - b*BSZ)<<18) | (unsigned)s;
    bk_in[i] = (unsigned short)b;
  }
  int h0 = cnt[(size_t)c*NBUCK + t];
  int h1 = (c+1 < NCHUNK) ? cnt[(size_t)(c+1)*NBUCK + t] : total[t];
  int hv = h1 - h0;                        // this chunk's count for bucket t
  sd[t] = hv; __syncthreads();
  #pragma unroll
  for(int o=1; o<1024; o<<=1){
    int x = (t>=o) ? sd[t-o] : 0;
    __syncthreads();
    sd[t] += x;
    __syncthreads();
  }
  {
    int ex = sd[t] - hv;
    excl[t] = ex; cur[t] = ex;
    base[t] = bbase[t] + h0;
  }
  __syncthreads();
  for(int i=t; i<n; i+=1024){
    int b = bk_in[i];
    int slot = atomicAdd(&cur[b], 1);
    sorted[slot] = pin[i];
    sbkt[slot]   = (unsigned short)b;
  }
  __syncthreads();
  for(int i=t; i<n; i+=1024){
    int b = sbkt[i];
    binned[ base[b] + (i - excl[b]) ] = sorted[i];   // contiguous runs per bucket
  }
}

// ---------------- phase D: per-bucket SRC-BIN sort, LDS-staged coalesced output ----------------
__global__ __launch_bounds__(512) void k_sub(const unsigned int* __restrict__ binned,
                                             const int* __restrict__ bbase,
                                             unsigned int* __restrict__ binned2,
                                             float* __restrict__ dinv, int N){
  __shared__ int hd[BSZ];        // dst_local degree histogram
  __shared__ int hs[SRCB];       // src-bin histogram
  __shared__ int cur[SRCB];
  __shared__ int sd[512];
  __shared__ unsigned int stage[SUBCAP];   // 32 KB
  int b = blockIdx.x;
  int t = threadIdx.x;
  if(t < BSZ)  hd[t] = 0;
  if(t < SRCB) hs[t] = 0;
  __syncthreads();
  int s0 = bbase[b], s1 = bbase[b+1];
  for(int i=s0+t; i<s1; i+=512){
    unsigned p = binned[i];
    atomicAdd(&hd[p>>18], 1);
    atomicAdd(&hs[(p & 0x3FFFF)>>9], 1);
  }
  __syncthreads();
  if(t < BSZ){
    int node = b*BSZ + t;
    if(node < N) dinv[node] = 1.0f / sqrtf((float)hd[t] + 1.0f);
  }
  int hv = (t<SRCB) ? hs[t] : 0;
  sd[t] = hv; __syncthreads();
  #pragma unroll
  for(int o=1; o<512; o<<=1){
    int x = (t>=o) ? sd[t-o] : 0;
    __syncthreads();
    sd[t] += x;
    __syncthreads();
  }
  if(t<SRCB) cur[t] = sd[t] - hv;          // stage-relative
  __syncthreads();
  int len = s1 - s0;
  if(len <= SUBCAP){
    for(int i=s0+t; i<s1; i+=512){
      unsigned p = binned[i];
      int slot = atomicAdd(&cur[(p & 0x3FFFF)>>9], 1);
      stage[slot] = p;
    }
    __syncthreads();
    for(int i=t; i<len; i+=512) binned2[s0 + i] = stage[i];   // coalesced
  } else {                                 // degenerate fallback: direct scatter
    for(int i=s0+t; i<s1; i+=512){
      unsigned p = binned[i];
      int slot = atomicAdd(&cur[(p & 0x3FFFF)>>9], 1);
      binned2[s0 + slot] = p;
    }
  }
}

// ---------------- h init: embedding gather + stats[0] (multi-copy fp32 atomics) ----------------
__global__ __launch_bounds__(256) void k_init_h(const int* __restrict__ x, const float* __restrict__ emb,
                                                float* __restrict__ h, float* __restrict__ stats0, int N){
  int i = blockIdx.x*256 + threadIdx.x;
  float v[CH];
  #pragma unroll
  for(int c=0;c<CH;c++) v[c]=0.f;
  if(i < N){
    int tt = x[i];
    const float4* ep = (const float4*)(emb + (size_t)tt*CH);
    float4 a = ep[0], b = ep[1];
    float4* hp = (float4*)(h + (size_t)i*CH);
    hp[0] = a; hp[1] = b;
    v[0]=a.x; v[1]=a.y; v[2]=a.z; v[3]=a.w; v[4]=b.x; v[5]=b.y; v[6]=b.z; v[7]=b.w;
  }
  float s[CH], q[CH];
  #pragma unroll
  for(int c=0;c<CH;c++){ s[c]=v[c]; q[c]=v[c]*v[c]; }
  #pragma unroll
  for(int off=32; off>0; off>>=1){
    #pragma unroll
    for(int c=0;c<CH;c++){ s[c]+=__shfl_down(s[c],off); q[c]+=__shfl_down(q[c],off); }
  }
  __shared__ float ls[4][2*CH];
  int wave = threadIdx.x>>6, lane = threadIdx.x&63;
  if(lane==0){
    #pragma unroll
    for(int c=0;c<CH;c++){ ls[wave][c]=s[c]; ls[wave][CH+c]=q[c]; }
  }
  __syncthreads();
  if(threadIdx.x < 2*CH){
    float tsum = ls[0][threadIdx.x]+ls[1][threadIdx.x]+ls[2][threadIdx.x]+ls[3][threadIdx.x];
    unsafeAtomicAdd(&stats0[(threadIdx.x*SCOP + (blockIdx.x & (SCOP-1)))*SPAD], tsum);
  }
}

// ---------------- per-node transform: reduce stat copies, fold BN, hts = int16((h@A+c0)*dinv*2^11) ----------------
__global__ __launch_bounds__(256) void k_ht(const float* __restrict__ h, const float* __restrict__ stats_l,
                                            const float* __restrict__ gamma, const float* __restrict__ beta,
                                            const float* __restrict__ convw,
                                            const float* __restrict__ dinv,
                                            short* __restrict__ hts, int l, int N){
  __shared__ float A[CH*CH], c0[CH], sA[CH], sT[CH];
  int t = threadIdx.x;
  if(t < CH){
    float mu = 0.f, ex2 = 0.f;
    #pragma unroll
    for(int c=0;c<SCOP;c++){
      mu  += stats_l[((t   )*SCOP + c)*SPAD];
      ex2 += stats_l[((CH+t)*SCOP + c)*SPAD];
    }
    const float invN = 1.0f / (float)NNODES;
    mu *= invN; ex2 *= invN;
    float var = ex2 - mu*mu;
    float r   = 1.0f / sqrtf(var + BN_EPS);
    float sc  = r * gamma[l*CH+t];
    sA[t] = sc;
    sT[t] = beta[l*CH+t] - mu*sc;
  }
  __syncthreads();
  if(t < CH*CH){
    int ci = t>>3, co = t&7;
    A[t] = sA[ci] * convw[(l*CH+ci)*CH+co];
  }
  if(t < CH){
    float a = 0.f;
    #pragma unroll
    for(int ci=0;ci<CH;ci++) a += sT[ci]*convw[(l*CH+ci)*CH+t];
    c0[t] = a;
  }
  __syncthreads();
  int i = blockIdx.x*blockDim.x + threadIdx.x;
  if(i >= N) return;
  const float4* hp = (const float4*)(h + (size_t)i*CH);
  float4 a = hp[0], b = hp[1];
  float v[CH] = {a.x,a.y,a.z,a.w,b.x,b.y,b.z,b.w};
  float o[CH];
  #pragma unroll
  for(int co=0;co<CH;co++) o[co]=c0[co];
  #pragma unroll
  for(int ci=0;ci<CH;ci++){
    float vv = v[ci];
    #pragma unroll
    for(int co=0;co<CH;co++) o[co] += vv*A[ci*CH+co];
  }
  float dn = dinv[i] * I16SCALE;
  union { short ss[CH]; uint4 u; } pk;
  #pragma unroll
  for(int c=0;c<CH;c++){
    float val = fminf(fmaxf(o[c]*dn, -32767.f), 32767.f);
    pk.ss[c] = (short)__float2int_rn(val);
  }
  *(uint4*)(hts + (size_t)i*CH) = pk.u;
}

// ---------------- src-sorted bucket push + FUSED finalize (int16 gather, direct ds_add) ----------------
// 1024 blocks (4/CU balanced), 512 threads, 8 lanes/edge.
// int16 fixed-point hts: gather sign-extends, LDS int atomic adds directly (zero
// per-edge conversion VALU). acc stride 9 kills the stride-8 inter-group bank aliasing.
__global__ __launch_bounds__(512) void k_push(const unsigned int* __restrict__ binned2,
                                              const int* __restrict__ bbase,
                                              const short* __restrict__ hts,
                                              const float* __restrict__ dinv,
                                              const float* __restrict__ convb,
                                              float* __restrict__ h, float* __restrict__ stats_next,
                                              int l, int N){
  __shared__ int acc[BSZ*ACCS];      // 6.9 KB, fixed-point 2^11, stride 9
  __shared__ unsigned est[ESTG];     // 2 KB edge stage
  int b = blockIdx.x, t = threadIdx.x;
  for(int i=t; i<BSZ*ACCS; i+=512) acc[i] = 0;
  __syncthreads();
  int s0 = bbase[b], s1 = bbase[b+1];
  int lane8 = t & 7;
  int g = t >> 3;                          // 0..63
  for(int off = s0; off < s1; off += ESTG){
    int n = min(ESTG, s1 - off);
    if(t < n) est[t] = binned2[off + t];   // coalesced
    __syncthreads();
    for(int e = g*4; e < n; e += 256){
      int m = n - e;
      if(m >= 4){
        unsigned p0 = est[e], p1 = est[e+1], p2 = est[e+2], p3 = est[e+3];  // ds_read broadcast
        int v0 = (int)hts[(size_t)(p0 & 0x3FFFF)*CH + lane8];   // sext short load
        int v1 = (int)hts[(size_t)(p1 & 0x3FFFF)*CH + lane8];
        int v2 = (int)hts[(size_t)(p2 & 0x3FFFF)*CH + lane8];
        int v3 = (int)hts[(size_t)(p3 & 0x3FFFF)*CH + lane8];
        atomicAdd(&acc[(p0>>18)*ACCS + lane8], v0);
        atomicAdd(&acc[(p1>>18)*ACCS + lane8], v1);
        atomicAdd(&acc[(p2>>18)*ACCS + lane8], v2);
        atomicAdd(&acc[(p3>>18)*ACCS + lane8], v3);
      } else {
        for(int i=0; i<m; i++){
          unsigned p = est[e+i];
          int v = (int)hts[(size_t)(p & 0x3FFFF)*CH + lane8];
          atomicAdd(&acc[(p>>18)*ACCS + lane8], v);
        }
      }
    }
    __syncthreads();
  }
  // epilogue: thread t<BSZ owns node b*BSZ+t (this block exclusively owns these dsts)
  float vv[CH];
  #pragma unroll
  for(int c=0;c<CH;c++) vv[c]=0.f;
  int node = b*BSZ + t;
  if(t < BSZ && node < N){
    float av[CH];
    #pragma unroll
    for(int c=0;c<CH;c++) av[c] = (float)acc[t*ACCS + c] * I16INV;
    union { short ss[CH]; uint4 u; } su;
    su.u = *(const uint4*)(hts + (size_t)node*CH);          // self loop (pre-scaled)
    const float4* hp = (const float4*)(h + (size_t)node*CH);
    float4 h0 = hp[0], h1 = hp[1];
    float hv2[CH] = {h0.x,h0.y,h0.z,h0.w,h1.x,h1.y,h1.z,h1.w};
    float dn = dinv[node];
    #pragma unroll
    for(int c=0;c<CH;c++){
      float sv = (float)su.ss[c] * I16INV;
      float r = hv2[c] + convb[l*CH + c] + dn*(av[c] + sv);
      vv[c] = fmaxf(r, 0.f);
    }
    float4* hw4 = (float4*)(h + (size_t)node*CH);
    hw4[0] = make_float4(vv[0],vv[1],vv[2],vv[3]);
    hw4[1] = make_float4(vv[4],vv[5],vv[6],vv[7]);
  }
  // next-layer BN stats (multi-copy atomics: copy = b & 15)
  float s[CH], q[CH];
  #pragma unroll
  for(int c=0;c<CH;c++){ s[c]=vv[c]; q[c]=vv[c]*vv[c]; }
  #pragma unroll
  for(int off=32; off>0; off>>=1){
    #pragma unroll
    for(int c=0;c<CH;c++){ s[c]+=__shfl_down(s[c],off); q[c]+=__shfl_down(q[c],off); }
  }
  __shared__ float ls[8][2*CH];
  int wave = t>>6, lane = t&63;
  if(lane==0){
    #pragma unroll
    for(int c=0;c<CH;c++){ ls[wave][c]=s[c]; ls[wave][CH+c]=q[c]; }
  }
  __syncthreads();
  if(t < 2*CH){
    float tot = 0.f;
    #pragma unroll
    for(int w=0; w<8; w++) tot += ls[w][t];
    unsafeAtomicAdd(&stats_next[(t*SCOP + (b & (SCOP-1)))*SPAD], tot);
  }
}

// ---------------- entries: u = xe@W1, v = xe@W2 + hb ----------------
__global__ __launch_bounds__(256) void k_uv(const int* __restrict__ entry, const float* __restrict__ h,
                                            const float* __restrict__ hw, const float* __restrict__ hb,
                                            float* __restrict__ u, float* __restrict__ v){
  __shared__ float w[2*CH*HID];
  __shared__ float b[HID];
  for(int t=threadIdx.x; t<2*CH*HID; t+=256) w[t]=hw[t];
  if(threadIdx.x<HID) b[threadIdx.x]=hb[threadIdx.x];
  __syncthreads();
  int k = blockIdx.x*blockDim.x + threadIdx.x;
  if(k >= NENT) return;
  int node = entry[k];
  const float4* hp = (const float4*)(h + (size_t)node*CH);
  float4 a = hp[0], b4 = hp[1];
  float xe[CH] = {a.x,a.y,a.z,a.w,b4.x,b4.y,b4.z,b4.w};
  #pragma unroll 4
  for(int c=0;c<HID;c++){
    float uu = 0.f, vv = b[c];
    #pragma unroll
    for(int ci=0;ci<CH;ci++){
      uu += xe[ci]*w[ci*HID+c];
      vv += xe[ci]*w[(CH+ci)*HID+c];
    }
    u[(size_t)k*HID+c] = uu;
    v[(size_t)k*HID+c] = vv;
  }
}

// ---------------- pairwise scorer ----------------
__global__ __launch_bounds__(256) void k_pair(const float* __restrict__ u, const float* __restrict__ v,
                                              const float* __restrict__ ow, const float* __restrict__ ob,
                                              float* __restrict__ out){
  __shared__ float us[16][HID+1];
  __shared__ float vs[64][HID+1];
  __shared__ float wo[HID];
  int tid = threadIdx.x;
  int jb = blockIdx.x*64, ib = blockIdx.y*16;
  for(int t=tid; t<16*HID; t+=256) us[t>>5][t&31] = u[(size_t)(ib + (t>>5))*HID + (t&31)];
  for(int t=tid; t<64*HID; t+=256) vs[t>>5][t&31] = v[(size_t)(jb + (t>>5))*HID + (t&31)];
  if(tid<HID) wo[tid]=ow[tid];
  __syncthreads();
  int tx = tid&63, ty = tid>>6;
  float a0=0.f, a1=0.f, a2=0.f, a3=0.f;
  #pragma unroll
  for(int c=0;c<HID;c++){
    float vv = vs[tx][c];
    float w  = wo[c];
    a0 += fmaxf(us[ty   ][c]+vv, 0.f)*w;
    a1 += fmaxf(us[ty+4 ][c]+vv, 0.f)*w;
    a2 += fmaxf(us[ty+8 ][c]+vv, 0.f)*w;
    a3 += fmaxf(us[ty+12][c]+vv, 0.f)*w;
  }
  float o0 = ob[0];
  size_t base = (size_t)ib*2048 + jb + tx;
  out[base + (size_t)(ty   )*2048] = a0+o0;
  out[base + (size_t)(ty+4 )*2048] = a1+o0;
  out[base + (size_t)(ty+8 )*2048] = a2+o0;
  out[base + (size_t)(ty+12)*2048] = a3+o0;
}

extern "C" void kernel_launch(void* const* d_in, const int* in_sizes, int n_in,
                              void* d_out, int out_size, void* d_ws, size_t ws_size,
                              hipStream_t stream){
  const int*   x     = (const int*)d_in[0];
  const int*   ei    = (const int*)d_in[1];
  const int*   entry = (const int*)d_in[2];
  const float* emb   = (const float*)d_in[3];
  const float* gamma = (const float*)d_in[4];
  const float* beta  = (const float*)d_in[5];
  const float* convw = (const float*)d_in[6];
  const float* convb = (const float*)d_in[7];
  const float* hw    = (const float*)d_in[8];
  const float* hb    = (const float*)d_in[9];
  const float* ow    = (const float*)d_in[10];
  const float* ob    = (const float*)d_in[11];
  const int* srcp = ei;
  const int* dstp = ei + NEDGES;

  // workspace (~72 MB)
  char* ws = (char*)d_ws;
  size_t o = 0;
  auto alloc = [&](size_t bytes){ void* p = ws + o; o += (bytes + 255) & ~(size_t)255; return p; };
  int*      cnt    = (int*)     alloc((size_t)NCHUNK*NBUCK*4);   // 6.4 MB
  int*      total  = (int*)     alloc(NBUCK*4);
  int*      bbase  = (int*)     alloc((NBUCK+1)*4);
  unsigned* binned = (unsigned*)alloc((size_t)NEDGES*4);         // 25.6 MB (dst-bucket runs)
  unsigned* binned2= (unsigned*)alloc((size_t)NEDGES*4);         // 25.6 MB (src-sorted runs)
  float*    dinv   = (float*)   alloc(NNODES*4);
  float*    h      = (float*)   alloc((size_t)NNODES*CH*4);
  short*    hts    = (short*)   alloc((size_t)NNODES*CH*2);      // 3.2 MB int16 fixed-point
  float*    stats  = (float*)   alloc((size_t)(NCONV+1)*SSLOT*4);// 147 KB (multi-copy, line-padded)
  float*    ub     = (float*)   alloc((size_t)NENT*HID*4);
  float*    vb     = (float*)   alloc((size_t)NENT*HID*4);
  (void)ws_size; (void)in_sizes; (void)n_in; (void)out_size;

  // ---- deterministic CSR build + src-bin re-sort ----
  k_chist<<<NCHUNK, 256, 0, stream>>>(dstp, cnt, NEDGES);
  k_cscan<<<NBUCK, 256, 0, stream>>>(cnt, total);
  k_bscan<<<1, 1024, 0, stream>>>(total, bbase);
  k_bin  <<<NCHUNK, 1024, 0, stream>>>(srcp, dstp, cnt, total, bbase, binned, NEDGES);
  k_sub  <<<NBUCK, 512, 0, stream>>>(binned, bbase, binned2, dinv, NNODES);

  hipMemsetAsync(stats, 0, (size_t)(NCONV+1)*SSLOT*sizeof(float), stream);
  k_init_h<<<(NNODES+255)/256, 256, 0, stream>>>(x, emb, h, stats, NNODES);

  for(int l=0; l<NCONV; l++){
    k_ht  <<<(NNODES+255)/256, 256, 0, stream>>>(h, stats + (size_t)l*SSLOT, gamma, beta, convw,
                                                 dinv, hts, l, NNODES);
    k_push<<<NBUCK, 512, 0, stream>>>(binned2, bbase, hts, dinv, convb, h,
                                      stats + (size_t)(l+1)*SSLOT, l, NNODES);
  }

  k_uv<<<NENT/256, 256, 0, stream>>>(entry, h, hw, hb, ub, vb);
  dim3 pg(2048/64, 2048/16);
  k_pair<<<pg, 256, 0, stream>>>(ub, vb, ow, ob, (float*)d_out);
}